// Round 7
// baseline (349.351 us; speedup 1.0000x reference)
//
#include <hip/hip_runtime.h>
#include <hip/hip_bf16.h>

using bf16 = __hip_bfloat16;
typedef __attribute__((ext_vector_type(8))) short short8;
typedef __attribute__((ext_vector_type(4))) float f32x4;

__device__ __forceinline__ unsigned short f2bf(float f) {
  bf16 h = __float2bfloat16(f);
  return *reinterpret_cast<unsigned short*>(&h);
}

__device__ __forceinline__ float loadf(const void* p, int i, int is_f32) {
  if (is_f32) return ((const float*)p)[i];
  return __bfloat162float(((const bf16*)p)[i]);
}

// ---------------------------------------------------------------------------
// detect input encodings by content (deterministic):
// flags[0] = floats are f32, flags[1] = edges are int64
// ---------------------------------------------------------------------------
__global__ __launch_bounds__(1024) void detect_kernel(
    const int* __restrict__ ei, const unsigned short* __restrict__ x,
    int* __restrict__ flags) {
  __shared__ int red[1024];
  int t = threadIdx.x;
  int o = 0;
  for (int i = t; i < 2048; i += 1024) o |= ei[2 * i + 1];
  int big = 0;
  for (int i = t; i < 2048; i += 1024) {
    float v = __uint_as_float(((unsigned)x[2 * i]) << 16);
    if (!(fabsf(v) < 1000.f)) big = 1;
  }
  red[t] = o;
  __syncthreads();
  for (int d = 512; d > 0; d >>= 1) {
    if (t < d) red[t] |= red[t + d];
    __syncthreads();
  }
  int o_all = red[0];
  __syncthreads();
  red[t] = big;
  __syncthreads();
  for (int d = 512; d > 0; d >>= 1) {
    if (t < d) red[t] |= red[t + d];
    __syncthreads();
  }
  if (t == 0) {
    flags[0] = red[0];
    flags[1] = (o_all == 0) ? 1 : 0;
  }
}

__device__ __forceinline__ int edge_src(const int* ei, int E, int e, int i64) {
  return i64 ? ei[2 * e] : ei[e];
}
__device__ __forceinline__ int edge_dst(const int* ei, int E, int e, int i64) {
  return i64 ? ei[2 * E + 2 * e] : ei[E + e];
}

// ---------------------------------------------------------------------------
// prep (both layers in one launch):
//   vj[h*64+f] = sum_c att_j[h,c] * W[h*64+c, f]       (8x64 fp32)
//   Wrt[c*512 + k'] = W[(h*64+c)*64 + f], k' = f*8+h   (64x512 bf16)
// ---------------------------------------------------------------------------
__global__ __launch_bounds__(256) void prep_all(
    const void* __restrict__ W1, const void* __restrict__ att1,
    const void* __restrict__ W2, const void* __restrict__ att2,
    const int* __restrict__ flags, float* __restrict__ vj1,
    bf16* __restrict__ Wrt1, float* __restrict__ vj2,
    bf16* __restrict__ Wrt2) {
  int is_f32 = flags[0];
  int side = blockIdx.x >= 128;
  const void* W = side ? W2 : W1;
  const void* att = side ? att2 : att1;
  float* vj = side ? vj2 : vj1;
  bf16* Wrt = side ? Wrt2 : Wrt1;
  int t = (blockIdx.x & 127) * 256 + threadIdx.x;
  if (t < 32768) {
    int c = t >> 9, k = t & 511;
    int f = k >> 3, h = k & 7;
    Wrt[t] = __float2bfloat16(loadf(W, ((h << 6) + c) * 64 + f, is_f32));
  }
  if (t < 512) {
    int hh = t >> 6, ff = t & 63;
    float s = 0.f;
    for (int cc = 0; cc < 64; ++cc)
      s += loadf(att, hh * 128 + 64 + cc, is_f32) *
           loadf(W, ((hh << 6) + cc) * 64 + ff, is_f32);
    vj[t] = s;
  }
}

// ---------------------------------------------------------------------------
// node transform (both node sets in one launch): h = elu(x@W.T+b) -> bf16,
// op side also computes a_j = h . v_j per head
// ---------------------------------------------------------------------------
template <int FIN>
__device__ __forceinline__ void node_body(
    const void* x, const void* W, const void* b, int is_f32,
    const float* vj, bf16* h_out, float* aj_out, int n) {
  int lane = threadIdx.x & 63;
  float acc = loadf(b, lane, is_f32);
#pragma unroll
  for (int f = 0; f < FIN; ++f)
    acc += loadf(x, n * FIN + f, is_f32) * loadf(W, lane * FIN + f, is_f32);
  float hv = acc > 0.f ? acc : expm1f(acc);
  h_out[(size_t)n * 64 + lane] = __float2bfloat16(hv);
  if (aj_out) {
#pragma unroll
    for (int hh = 0; hh < 8; ++hh) {
      float p = hv * vj[hh * 64 + lane];
#pragma unroll
      for (int o = 32; o >= 1; o >>= 1) p += __shfl_xor(p, o, 64);
      if (lane == 0) aj_out[(size_t)n * 8 + hh] = p;
    }
  }
}

__global__ __launch_bounds__(256) void node_all(
    const void* __restrict__ x_op, const void* __restrict__ W_op,
    const void* __restrict__ b_op, const void* __restrict__ x_mc,
    const void* __restrict__ W_mc, const void* __restrict__ b_mc,
    const int* __restrict__ flags, const float* __restrict__ vj,
    bf16* __restrict__ h_op, float* __restrict__ aj_op,
    bf16* __restrict__ h_mc, int n_op, int n_mc, int nbo) {
  int is_f32 = flags[0];
  int wave = threadIdx.x >> 6;
  if ((int)blockIdx.x < nbo) {
    int n = blockIdx.x * 4 + wave;
    if (n < n_op) node_body<4>(x_op, W_op, b_op, is_f32, vj, h_op, aj_op, n);
  } else {
    int n = (blockIdx.x - nbo) * 4 + wave;
    if (n < n_mc)
      node_body<2>(x_mc, W_mc, b_mc, is_f32, nullptr, h_mc, nullptr, n);
  }
}

// ---------------------------------------------------------------------------
// CSR build: count, 3-stage parallel exclusive scan (both sides merged), fill
// ---------------------------------------------------------------------------
__global__ __launch_bounds__(256) void count_edges(
    const int* __restrict__ ei, int E, const int* __restrict__ flags,
    int* __restrict__ cnt_dst, int* __restrict__ cnt_src) {
  int i64 = flags[1];
  int e = blockIdx.x * blockDim.x + threadIdx.x;
  if (e < E) {
    atomicAdd(&cnt_dst[edge_dst(ei, E, e, i64)], 1);
    atomicAdd(&cnt_src[edge_src(ei, E, e, i64)], 1);
  }
}

__global__ __launch_bounds__(256) void scan_bsum2(
    const int* __restrict__ cnt1, int n1, int nb1, const int* __restrict__ cnt2,
    int n2, int* __restrict__ bsum1, int* __restrict__ bsum2) {
  __shared__ int red[256];
  int t = threadIdx.x;
  int side = (int)blockIdx.x >= nb1;
  const int* cnt = side ? cnt2 : cnt1;
  int n = side ? n2 : n1;
  int blk = side ? (blockIdx.x - nb1) : blockIdx.x;
  int base = blk * 2048 + t * 8;
  int s = 0;
#pragma unroll
  for (int i = 0; i < 8; ++i)
    if (base + i < n) s += cnt[base + i];
  red[t] = s;
  __syncthreads();
  for (int d = 128; d > 0; d >>= 1) {
    if (t < d) red[t] += red[t + d];
    __syncthreads();
  }
  if (t == 0) (side ? bsum2 : bsum1)[blk] = red[0];
}

__global__ __launch_bounds__(128) void scan_btop2(
    const int* __restrict__ bsum1, int nb1, int* __restrict__ bscan1,
    int* __restrict__ offs1, int n1, const int* __restrict__ bsum2, int nb2,
    int* __restrict__ bscan2, int* __restrict__ offs2, int n2) {
  int t = threadIdx.x;
  if (t == 0) {
    int run = 0;
    for (int b = 0; b < nb1; ++b) {
      bscan1[b] = run;
      run += bsum1[b];
    }
    offs1[n1] = run;
  }
  if (t == 64) {
    int run = 0;
    for (int b = 0; b < nb2; ++b) {
      bscan2[b] = run;
      run += bsum2[b];
    }
    offs2[n2] = run;
  }
}

__global__ __launch_bounds__(256) void scan_write2(
    const int* __restrict__ cnt1, int n1, int nb1,
    const int* __restrict__ bscan1, int* __restrict__ offs1,
    int* __restrict__ cur1, const int* __restrict__ cnt2, int n2,
    const int* __restrict__ bscan2, int* __restrict__ offs2,
    int* __restrict__ cur2) {
  __shared__ int red[256];
  int t = threadIdx.x;
  int side = (int)blockIdx.x >= nb1;
  const int* cnt = side ? cnt2 : cnt1;
  const int* bscan = side ? bscan2 : bscan1;
  int* offs = side ? offs2 : offs1;
  int* cur = side ? cur2 : cur1;
  int n = side ? n2 : n1;
  int blk = side ? (blockIdx.x - nb1) : blockIdx.x;
  int base = blk * 2048 + t * 8;
  int c[8];
  int s = 0;
#pragma unroll
  for (int i = 0; i < 8; ++i) {
    c[i] = (base + i < n) ? cnt[base + i] : 0;
    s += c[i];
  }
  red[t] = s;
  __syncthreads();
  for (int d = 1; d < 256; d <<= 1) {
    int v = red[t];
    int add = (t >= d) ? red[t - d] : 0;
    __syncthreads();
    red[t] = v + add;
    __syncthreads();
  }
  int run = bscan[blk] + red[t] - s;
#pragma unroll
  for (int i = 0; i < 8; ++i) {
    if (base + i < n) {
      offs[base + i] = run;
      cur[base + i] = run;
      run += c[i];
    }
  }
}

__global__ __launch_bounds__(256) void fill_edges(
    const int* __restrict__ ei, int E, const int* __restrict__ flags,
    int* __restrict__ cur1, int* __restrict__ srcs1, int* __restrict__ cur2,
    int* __restrict__ srcs2) {
  int i64 = flags[1];
  int e = blockIdx.x * blockDim.x + threadIdx.x;
  if (e < E) {
    int s = edge_src(ei, E, e, i64), d = edge_dst(ei, E, e, i64);
    int p = atomicAdd(&cur1[d], 1);
    srcs1[p] = s;
    int q = atomicAdd(&cur2[s], 1);
    srcs2[q] = d;
  }
}

// ---------------------------------------------------------------------------
// fused GAT (stats + gather + MFMA epilogue), 16 dsts/block, 4 dsts/wave:
//  phase 1: per-(dst,head) online softmax stats; lanes = (slot, head, half);
//           slot=t>>4 aligns each wave to its OWN 4 dsts -> no barrier needed
//  phase 2: chunked gather; per chunk compute normalized weights on the fly
//           into LDS, then lockstep-4 rounds (one edge per dst per round ->
//           4 independent row loads in flight, z[4][8] statically indexed)
//  epilogue: 16x512 @ 512x64 block MFMA + residual + ELU (+ aj_next)
// ---------------------------------------------------------------------------
template <bool WRITE_AJ, bool SRC_F32>
__global__ __launch_bounds__(256) void gat_fused(
    int Nd, const int* __restrict__ offs, const int* __restrict__ srcs,
    const float* __restrict__ aj, const void* __restrict__ h_src,
    const bf16* __restrict__ Wrt, const bf16* __restrict__ h_res,
    float* __restrict__ out_f32, const float* __restrict__ vj_next,
    float* __restrict__ aj_next) {
  __shared__ __align__(16) unsigned short Zl[16 * 520];  // 16.3 KB
  __shared__ float ajp[4][16][8];                        // 2 KB
  __shared__ int srcs_s[4][32];                          // 0.5 KB
  __shared__ float ew_s[4][256];                         // 4 KB
  __shared__ float mj_s[16][8], si_s[16][8];             // 1 KB

  int t = threadIdx.x;
  int wv = t >> 6, lane = t & 63;
  int d0 = blockIdx.x * 16;

  // ---- phase 1: softmax stats, 2-way edge-split per (dst,head) ----
  {
    int slot = t >> 4, h = (t >> 1) & 7, half = t & 1;
    int d = d0 + slot;
    float m = -INFINITY, s = 0.f;
    if (d < Nd) {
      int beg = offs[d], ne = offs[d + 1] - beg;
      for (int e = half; e < ne; e += 2) {
        float a = aj[(size_t)srcs[beg + e] * 8 + h];
        float mn = fmaxf(m, a);
        s = s * __expf(m - mn) + __expf(a - mn);
        m = mn;
      }
    }
    float mo = __shfl_xor(m, 1, 64);
    float so = __shfl_xor(s, 1, 64);
    float mn = fmaxf(m, mo);
    float sn = (s > 0.f ? s * __expf(m - mn) : 0.f) +
               (so > 0.f ? so * __expf(mo - mn) : 0.f);
    if (half == 0) {
      mj_s[slot][h] = mn;
      si_s[slot][h] = 1.f / (sn + 1e-16f);
    }
  }
  // wave wv wrote slots wv*4..wv*4+3 and only reads those below:
  // same-wave LDS dependency, compiler-ordered; no __syncthreads.

  float z[4][8];
#pragma unroll
  for (int j = 0; j < 4; ++j)
#pragma unroll
    for (int h = 0; h < 8; ++h) z[j][h] = 0.f;

  int dlo = d0 + wv * 4;
  if (dlo < Nd) {
    int o[5];
#pragma unroll
    for (int j = 0; j <= 4; ++j) o[j] = offs[min(dlo + j, Nd)];
    int beg = o[0], end = o[4];
    for (int cb = beg; cb < end; cb += 32) {
      int cn = min(32, end - cb);
      if (lane < cn) srcs_s[wv][lane] = srcs[cb + lane];
      // normalized weights for this chunk (on the fly)
      for (int i = lane; i < cn * 8; i += 64) {
        int e = i >> 3, h = i & 7;
        int ge = cb + e;
        int j = (ge >= o[1]) + (ge >= o[2]) + (ge >= o[3]);
        int slot = wv * 4 + j;
        float a = aj[(size_t)srcs_s[wv][e] * 8 + h];
        ew_s[wv][i] = __expf(a - mj_s[slot][h]) * si_s[slot][h];
      }
      // lockstep-4 rounds: one edge from each dst per round
      int c[4], ee[4];
#pragma unroll
      for (int j = 0; j < 4; ++j) {
        c[j] = max(cb, o[j]) - cb;
        ee[j] = min(cb + cn, o[j + 1]) - cb;
      }
      int rounds = 0;
#pragma unroll
      for (int j = 0; j < 4; ++j) rounds = max(rounds, ee[j] - c[j]);
      for (int r = 0; r < rounds; ++r) {
        float x[4];
        int ii[4];
        bool act[4];
#pragma unroll
        for (int j = 0; j < 4; ++j) {
          act[j] = c[j] < ee[j];
          ii[j] = act[j] ? c[j] : 0;
          int src = srcs_s[wv][ii[j]];
          size_t idx = (size_t)src * 64 + lane;
          float xv = SRC_F32 ? ((const float*)h_src)[idx]
                             : __bfloat162float(((const bf16*)h_src)[idx]);
          x[j] = act[j] ? xv : 0.f;
        }
#pragma unroll
        for (int j = 0; j < 4; ++j) {
#pragma unroll
          for (int h = 0; h < 8; ++h)
            z[j][h] += ew_s[wv][ii[j] * 8 + h] * x[j];
          c[j] += act[j] ? 1 : 0;
        }
      }
    }
  }

  // z -> LDS bf16: row = wv*4+j, elems k' = lane*8 + h (one b128 per dst)
#pragma unroll
  for (int j = 0; j < 4; ++j) {
    int4 pk;
    pk.x = ((int)f2bf(z[j][1]) << 16) | f2bf(z[j][0]);
    pk.y = ((int)f2bf(z[j][3]) << 16) | f2bf(z[j][2]);
    pk.z = ((int)f2bf(z[j][5]) << 16) | f2bf(z[j][4]);
    pk.w = ((int)f2bf(z[j][7]) << 16) | f2bf(z[j][6]);
    *(int4*)&Zl[(wv * 4 + j) * 520 + lane * 8] = pk;
  }
  __syncthreads();

  // MFMA epilogue: wave wv computes rows 0..15, cols wv*16..wv*16+15
  int row = lane & 15;
  int kg = lane >> 4;
  f32x4 acc = {0.f, 0.f, 0.f, 0.f};
#pragma unroll
  for (int kt = 0; kt < 16; ++kt) {
    int kbase = kt * 32 + kg * 8;
    short8 a = *(const short8*)&Zl[row * 520 + kbase];
    short8 b = *(const short8*)&Wrt[(size_t)(wv * 16 + row) * 512 + kbase];
    acc = __builtin_amdgcn_mfma_f32_16x16x32_bf16(a, b, acc, 0, 0, 0);
  }

  int col = wv * 16 + row;
  float o_r[4];
#pragma unroll
  for (int r = 0; r < 4; ++r) {
    int dloc = kg * 4 + r;
    int d = d0 + dloc;
    float o = 0.f;
    if (d < Nd) {
      float v = __bfloat162float(h_res[(size_t)d * 64 + col]) + 0.125f * acc[r];
      o = v > 0.f ? v : expm1f(v);
      out_f32[(size_t)d * 64 + col] = o;
    }
    o_r[r] = o;
  }

  if (WRITE_AJ) {
#pragma unroll
    for (int r = 0; r < 4; ++r) {
      int dloc = kg * 4 + r;
#pragma unroll
      for (int h = 0; h < 8; ++h) {
        float p = o_r[r] * vj_next[h * 64 + col];
        p += __shfl_xor(p, 1, 64);
        p += __shfl_xor(p, 2, 64);
        p += __shfl_xor(p, 4, 64);
        p += __shfl_xor(p, 8, 64);
        if (row == 0) ajp[wv][dloc][h] = p;
      }
    }
    __syncthreads();
    if (t < 128) {
      int dloc = t >> 3, h = t & 7;
      int d = d0 + dloc;
      if (d < Nd) {
        float s = ajp[0][dloc][h] + ajp[1][dloc][h] + ajp[2][dloc][h] +
                  ajp[3][dloc][h];
        aj_next[(size_t)d * 8 + h] = s;
      }
    }
  }
}

// ---------------------------------------------------------------------------
extern "C" void kernel_launch(void* const* d_in, const int* in_sizes, int n_in,
                              void* d_out, int out_size, void* d_ws,
                              size_t ws_size, hipStream_t stream) {
  const void* op_nodes = d_in[0];
  const void* mc_nodes = d_in[1];
  const int* ei        = (const int*)d_in[2];
  const void* W_op     = d_in[3];
  const void* b_op     = d_in[4];
  const void* W_mc     = d_in[5];
  const void* b_mc     = d_in[6];
  const void* W_om     = d_in[7];
  const void* att_om   = d_in[8];
  const void* W_mo     = d_in[9];
  const void* att_mo   = d_in[10];

  int n_op = in_sizes[0] / 4;
  int n_mc = in_sizes[1] / 2;
  int E    = in_sizes[2] / 2;

  char* ws = (char*)d_ws;
  size_t off = 0;
  auto alloc = [&](size_t bytes) -> void* {
    void* p = ws + off;
    off = (off + bytes + 255) & ~(size_t)255;
    return p;
  };
  int* flags   = (int*)alloc(16);
  bf16* h_op   = (bf16*)alloc((size_t)n_op * 64 * 2);
  bf16* h_mc   = (bf16*)alloc((size_t)n_mc * 64 * 2);
  float* aj_op = (float*)alloc((size_t)n_op * 8 * 4);
  float* aj_mc = (float*)alloc((size_t)n_mc * 8 * 4);
  float* vj_om = (float*)alloc(512 * 4);
  float* vj_mo = (float*)alloc(512 * 4);
  bf16* Wrt_om = (bf16*)alloc(32768 * 2);
  bf16* Wrt_mo = (bf16*)alloc(32768 * 2);
  int* cnt1  = (int*)alloc((size_t)n_mc * 4);
  int* cnt2  = (int*)alloc((size_t)n_op * 4);
  int* offs1 = (int*)alloc((size_t)(n_mc + 1) * 4);
  int* cur1  = (int*)alloc((size_t)n_mc * 4);
  int* srcs1 = (int*)alloc((size_t)E * 4);
  int* offs2 = (int*)alloc((size_t)(n_op + 1) * 4);
  int* cur2  = (int*)alloc((size_t)n_op * 4);
  int* srcs2 = (int*)alloc((size_t)E * 4);
  int* bsum1 = (int*)alloc(256 * 4);
  int* bsum2 = (int*)alloc(256 * 4);
  int* bscan1 = (int*)alloc(256 * 4);
  int* bscan2 = (int*)alloc(256 * 4);

  float* out_op = (float*)d_out;
  float* out_mc = out_op + (size_t)n_op * 64;  // layer-1 result + layer-2 src

  hipMemsetAsync(cnt1, 0, (size_t)n_mc * 4, stream);
  hipMemsetAsync(cnt2, 0, (size_t)n_op * 4, stream);

  detect_kernel<<<1, 1024, 0, stream>>>(ei, (const unsigned short*)op_nodes,
                                        flags);

  prep_all<<<256, 256, 0, stream>>>(W_om, att_om, W_mo, att_mo, flags, vj_om,
                                    Wrt_om, vj_mo, Wrt_mo);

  int nbo = (n_op + 3) / 4, nbm = (n_mc + 3) / 4;
  node_all<<<nbo + nbm, 256, 0, stream>>>(op_nodes, W_op, b_op, mc_nodes, W_mc,
                                          b_mc, flags, vj_om, h_op, aj_op, h_mc,
                                          n_op, n_mc, nbo);

  count_edges<<<(E + 255) / 256, 256, 0, stream>>>(ei, E, flags, cnt1, cnt2);

  int nb1 = (n_mc + 2047) / 2048, nb2 = (n_op + 2047) / 2048;
  scan_bsum2<<<nb1 + nb2, 256, 0, stream>>>(cnt1, n_mc, nb1, cnt2, n_op, bsum1,
                                            bsum2);
  scan_btop2<<<1, 128, 0, stream>>>(bsum1, nb1, bscan1, offs1, n_mc, bsum2, nb2,
                                    bscan2, offs2, n_op);
  scan_write2<<<nb1 + nb2, 256, 0, stream>>>(cnt1, n_mc, nb1, bscan1, offs1,
                                             cur1, cnt2, n_op, bscan2, offs2,
                                             cur2);
  fill_edges<<<(E + 255) / 256, 256, 0, stream>>>(ei, E, flags, cur1, srcs1,
                                                  cur2, srcs2);

  // GAT1: op -> mc (writes out_mc f32 + aj_mc for layer 2)
  gat_fused<true, false><<<(n_mc + 15) / 16, 256, 0, stream>>>(
      n_mc, offs1, srcs1, aj_op, h_op, Wrt_om, h_mc, out_mc, vj_mo, aj_mc);
  // GAT2: mc -> op (src = layer-1 mc output, f32 in d_out)
  gat_fused<false, true><<<(n_op + 15) / 16, 256, 0, stream>>>(
      n_op, offs2, srcs2, aj_mc, out_mc, Wrt_mo, h_op, out_op,
      (const float*)nullptr, (float*)nullptr);
}

// Round 8
// 313.473 us; speedup vs baseline: 1.1145x; 1.1145x over previous
//
#include <hip/hip_runtime.h>
#include <hip/hip_bf16.h>

using bf16 = __hip_bfloat16;
typedef __attribute__((ext_vector_type(8))) short short8;
typedef __attribute__((ext_vector_type(4))) float f32x4;

__device__ __forceinline__ unsigned short f2bf(float f) {
  bf16 h = __float2bfloat16(f);
  return *reinterpret_cast<unsigned short*>(&h);
}
__device__ __forceinline__ float bf2f(unsigned short u) {
  return __uint_as_float(((unsigned)u) << 16);
}

__device__ __forceinline__ float loadf(const void* p, int i, int is_f32) {
  if (is_f32) return ((const float*)p)[i];
  return __bfloat162float(((const bf16*)p)[i]);
}

// ---------------------------------------------------------------------------
// init: zero counters (all blocks) + dtype detection (block 0)
// flags[0] = floats are f32, flags[1] = edges are int64
// ---------------------------------------------------------------------------
__global__ __launch_bounds__(256) void init_kernel(
    const int* __restrict__ ei, const unsigned short* __restrict__ x,
    int* __restrict__ flags, int* __restrict__ cnt1, int n1,
    int* __restrict__ cnt2, int n2) {
  int t = threadIdx.x;
  int g = blockIdx.x * 256 + t;
  int stride = gridDim.x * 256;
  for (int i = g; i < n1; i += stride) cnt1[i] = 0;
  for (int i = g; i < n2; i += stride) cnt2[i] = 0;
  if (blockIdx.x == 0) {
    __shared__ int red[256];
    int o = 0, big = 0;
    for (int i = t; i < 2048; i += 256) {
      o |= ei[2 * i + 1];
      float v = __uint_as_float(((unsigned)x[2 * i]) << 16);
      if (!(fabsf(v) < 1000.f)) big = 1;
    }
    red[t] = o;
    __syncthreads();
    for (int d = 128; d > 0; d >>= 1) {
      if (t < d) red[t] |= red[t + d];
      __syncthreads();
    }
    int o_all = red[0];
    __syncthreads();
    red[t] = big;
    __syncthreads();
    for (int d = 128; d > 0; d >>= 1) {
      if (t < d) red[t] |= red[t + d];
      __syncthreads();
    }
    if (t == 0) {
      flags[0] = red[0];
      flags[1] = (o_all == 0) ? 1 : 0;
    }
  }
}

__device__ __forceinline__ int edge_src(const int* ei, int E, int e, int i64) {
  return i64 ? ei[2 * e] : ei[e];
}
__device__ __forceinline__ int edge_dst(const int* ei, int E, int e, int i64) {
  return i64 ? ei[2 * E + 2 * e] : ei[E + e];
}

// ---------------------------------------------------------------------------
// prep (both layers in one launch):
//   vj[h*64+f] = sum_c att_j[h,c] * W[h*64+c, f]       (8x64 fp32)
//   Wrt[c*512 + k'] = W[(h*64+c)*64 + f], k' = f*8+h   (64x512 bf16)
// ---------------------------------------------------------------------------
__global__ __launch_bounds__(256) void prep_all(
    const void* __restrict__ W1, const void* __restrict__ att1,
    const void* __restrict__ W2, const void* __restrict__ att2,
    const int* __restrict__ flags, float* __restrict__ vj1,
    bf16* __restrict__ Wrt1, float* __restrict__ vj2,
    bf16* __restrict__ Wrt2) {
  int is_f32 = flags[0];
  int side = blockIdx.x >= 128;
  const void* W = side ? W2 : W1;
  const void* att = side ? att2 : att1;
  float* vj = side ? vj2 : vj1;
  bf16* Wrt = side ? Wrt2 : Wrt1;
  int t = (blockIdx.x & 127) * 256 + threadIdx.x;
  if (t < 32768) {
    int c = t >> 9, k = t & 511;
    int f = k >> 3, h = k & 7;
    Wrt[t] = __float2bfloat16(loadf(W, ((h << 6) + c) * 64 + f, is_f32));
  }
  if (t < 512) {
    int hh = t >> 6, ff = t & 63;
    float s = 0.f;
    for (int cc = 0; cc < 64; ++cc)
      s += loadf(att, hh * 128 + 64 + cc, is_f32) *
           loadf(W, ((hh << 6) + cc) * 64 + ff, is_f32);
    vj[t] = s;
  }
}

// ---------------------------------------------------------------------------
// node transform (both node sets in one launch): h = elu(x@W.T+b) -> bf16,
// op side also computes a_j = h . v_j per head
// ---------------------------------------------------------------------------
template <int FIN>
__device__ __forceinline__ void node_body(
    const void* x, const void* W, const void* b, int is_f32,
    const float* vj, bf16* h_out, float* aj_out, int n) {
  int lane = threadIdx.x & 63;
  float acc = loadf(b, lane, is_f32);
#pragma unroll
  for (int f = 0; f < FIN; ++f)
    acc += loadf(x, n * FIN + f, is_f32) * loadf(W, lane * FIN + f, is_f32);
  float hv = acc > 0.f ? acc : expm1f(acc);
  h_out[(size_t)n * 64 + lane] = __float2bfloat16(hv);
  if (aj_out) {
#pragma unroll
    for (int hh = 0; hh < 8; ++hh) {
      float p = hv * vj[hh * 64 + lane];
#pragma unroll
      for (int o = 32; o >= 1; o >>= 1) p += __shfl_xor(p, o, 64);
      if (lane == 0) aj_out[(size_t)n * 8 + hh] = p;
    }
  }
}

__global__ __launch_bounds__(256) void node_all(
    const void* __restrict__ x_op, const void* __restrict__ W_op,
    const void* __restrict__ b_op, const void* __restrict__ x_mc,
    const void* __restrict__ W_mc, const void* __restrict__ b_mc,
    const int* __restrict__ flags, const float* __restrict__ vj,
    bf16* __restrict__ h_op, float* __restrict__ aj_op,
    bf16* __restrict__ h_mc, int n_op, int n_mc, int nbo) {
  int is_f32 = flags[0];
  int wave = threadIdx.x >> 6;
  if ((int)blockIdx.x < nbo) {
    int n = blockIdx.x * 4 + wave;
    if (n < n_op) node_body<4>(x_op, W_op, b_op, is_f32, vj, h_op, aj_op, n);
  } else {
    int n = (blockIdx.x - nbo) * 4 + wave;
    if (n < n_mc)
      node_body<2>(x_mc, W_mc, b_mc, is_f32, nullptr, h_mc, nullptr, n);
  }
}

// ---------------------------------------------------------------------------
// CSR build: count, 2-stage scan (block sums; write with inline prefix), fill
// ---------------------------------------------------------------------------
__global__ __launch_bounds__(256) void count_edges(
    const int* __restrict__ ei, int E, const int* __restrict__ flags,
    int* __restrict__ cnt_dst, int* __restrict__ cnt_src) {
  int i64 = flags[1];
  int e = blockIdx.x * blockDim.x + threadIdx.x;
  if (e < E) {
    atomicAdd(&cnt_dst[edge_dst(ei, E, e, i64)], 1);
    atomicAdd(&cnt_src[edge_src(ei, E, e, i64)], 1);
  }
}

__global__ __launch_bounds__(256) void scan_bsum2(
    const int* __restrict__ cnt1, int n1, int nb1, const int* __restrict__ cnt2,
    int n2, int* __restrict__ bsum1, int* __restrict__ bsum2) {
  __shared__ int red[256];
  int t = threadIdx.x;
  int side = (int)blockIdx.x >= nb1;
  const int* cnt = side ? cnt2 : cnt1;
  int n = side ? n2 : n1;
  int blk = side ? (blockIdx.x - nb1) : blockIdx.x;
  int base = blk * 2048 + t * 8;
  int s = 0;
#pragma unroll
  for (int i = 0; i < 8; ++i)
    if (base + i < n) s += cnt[base + i];
  red[t] = s;
  __syncthreads();
  for (int d = 128; d > 0; d >>= 1) {
    if (t < d) red[t] += red[t + d];
    __syncthreads();
  }
  if (t == 0) (side ? bsum2 : bsum1)[blk] = red[0];
}

__global__ __launch_bounds__(256) void scan_write2(
    const int* __restrict__ cnt1, int n1, int nb1,
    const int* __restrict__ bsum1, int* __restrict__ offs1,
    int* __restrict__ cur1, const int* __restrict__ cnt2, int n2, int nb2,
    const int* __restrict__ bsum2, int* __restrict__ offs2,
    int* __restrict__ cur2) {
  __shared__ int red[256];
  __shared__ int base_s;
  int t = threadIdx.x;
  int side = (int)blockIdx.x >= nb1;
  const int* cnt = side ? cnt2 : cnt1;
  const int* bsum = side ? bsum2 : bsum1;
  int* offs = side ? offs2 : offs1;
  int* cur = side ? cur2 : cur1;
  int n = side ? n2 : n1;
  int nb = side ? nb2 : nb1;
  int blk = side ? (blockIdx.x - nb1) : blockIdx.x;
  if (t == 0) {
    int b = 0;
    for (int i = 0; i < blk; ++i) b += bsum[i];
    base_s = b;
  }
  int base = blk * 2048 + t * 8;
  int c[8];
  int s = 0;
#pragma unroll
  for (int i = 0; i < 8; ++i) {
    c[i] = (base + i < n) ? cnt[base + i] : 0;
    s += c[i];
  }
  red[t] = s;
  __syncthreads();
  for (int d = 1; d < 256; d <<= 1) {
    int v = red[t];
    int add = (t >= d) ? red[t - d] : 0;
    __syncthreads();
    red[t] = v + add;
    __syncthreads();
  }
  int run = base_s + red[t] - s;
#pragma unroll
  for (int i = 0; i < 8; ++i) {
    if (base + i < n) {
      offs[base + i] = run;
      cur[base + i] = run;
      run += c[i];
    }
  }
  if (blk == nb - 1 && t == 255) offs[n] = base_s + red[255];
}

__global__ __launch_bounds__(256) void fill_edges(
    const int* __restrict__ ei, int E, const int* __restrict__ flags,
    int* __restrict__ cur1, int* __restrict__ srcs1, int* __restrict__ cur2,
    int* __restrict__ srcs2) {
  int i64 = flags[1];
  int e = blockIdx.x * blockDim.x + threadIdx.x;
  if (e < E) {
    int s = edge_src(ei, E, e, i64), d = edge_dst(ei, E, e, i64);
    int p = atomicAdd(&cur1[d], 1);
    srcs1[p] = s;
    int q = atomicAdd(&cur2[s], 1);
    srcs2[q] = d;
  }
}

// ---------------------------------------------------------------------------
// fused GAT v3: 16 dsts/block, 4 dsts/wave, QUARTER-WAVE streams.
//  phase 1: two-pass softmax stats (independent loads), lanes=(slot,h,half)
//  phase 2: chunked; ew on the fly into LDS; rounds: lane=(slot j=lane>>4,
//           fq=lane&15) -> one dwordx4 row-load serves 4 dsts at once,
//           ew via 2x ds_read_b128, z[8 heads][4 feats] in VGPRs
//  epilogue: 16x512 @ 512x64 block MFMA + residual + ELU (+ aj_next)
// ---------------------------------------------------------------------------
template <bool WRITE_AJ, bool SRC_F32>
__global__ __launch_bounds__(256) void gat_fused(
    int Nd, const int* __restrict__ offs, const int* __restrict__ srcs,
    const float* __restrict__ aj, const void* __restrict__ h_src,
    const bf16* __restrict__ Wrt, const bf16* __restrict__ h_res,
    float* __restrict__ out_f32, const float* __restrict__ vj_next,
    float* __restrict__ aj_next) {
  __shared__ __align__(16) unsigned short Zl[16 * 520];      // 16.3 KB
  __shared__ float ajp[4][16][8];                            // 2 KB
  __shared__ int srcs_s[4][32];                              // 0.5 KB
  __shared__ __align__(16) float ew_s[4][256];               // 4 KB
  __shared__ float mj_s[16][8], si_s[16][8];                 // 1 KB

  int t = threadIdx.x;
  int wv = t >> 6, lane = t & 63;
  int d0 = blockIdx.x * 16;

  // ---- phase 1: two-pass stats; lanes = (slot=t>>4, h=(t>>1)&7, half=t&1)
  {
    int slot = t >> 4, h = (t >> 1) & 7, half = t & 1;
    int d = d0 + slot;
    int beg = 0, ne = 0;
    if (d < Nd) {
      beg = offs[d];
      ne = offs[d + 1] - beg;
    }
    float m = -INFINITY;
#pragma unroll 4
    for (int e = half; e < ne; e += 2)
      m = fmaxf(m, aj[(size_t)srcs[beg + e] * 8 + h]);
    m = fmaxf(m, __shfl_xor(m, 1, 64));
    float s = 0.f;
#pragma unroll 4
    for (int e = half; e < ne; e += 2)
      s += __expf(aj[(size_t)srcs[beg + e] * 8 + h] - m);
    s += __shfl_xor(s, 1, 64);
    if (half == 0) {
      mj_s[slot][h] = m;
      si_s[slot][h] = 1.f / (s + 1e-16f);
    }
  }
  // stats for slots wv*4..wv*4+3 written by wave wv; read only by wave wv
  // below -> same-wave LDS ordering, no barrier needed.

  float z[8][4];  // [head][feat-in-quad]
#pragma unroll
  for (int h = 0; h < 8; ++h)
#pragma unroll
    for (int f = 0; f < 4; ++f) z[h][f] = 0.f;

  int sj = lane >> 4;   // quarter = dst slot within wave
  int fq = lane & 15;   // feature quad: features fq*4..fq*4+3
  int dlo = d0 + wv * 4;
  if (dlo < Nd) {
    int o0 = offs[min(dlo + 0, Nd)];
    int o1 = offs[min(dlo + 1, Nd)];
    int o2 = offs[min(dlo + 2, Nd)];
    int o3 = offs[min(dlo + 3, Nd)];
    int o4 = offs[min(dlo + 4, Nd)];
    int oj = sj == 0 ? o0 : sj == 1 ? o1 : sj == 2 ? o2 : o3;
    int oj1 = sj == 0 ? o1 : sj == 1 ? o2 : sj == 2 ? o3 : o4;
    for (int cb = o0; cb < o4; cb += 32) {
      int cn = min(32, o4 - cb);
      if (lane < cn) srcs_s[wv][lane] = srcs[cb + lane];
      for (int i = lane; i < cn * 8; i += 64) {
        int e = i >> 3, h = i & 7;
        int ge = cb + e;
        int j = (ge >= o1) + (ge >= o2) + (ge >= o3);
        int sl = wv * 4 + j;
        float a = aj[(size_t)srcs_s[wv][e] * 8 + h];
        ew_s[wv][i] = __expf(a - mj_s[sl][h]) * si_s[sl][h];
      }
      int c = max(cb, oj) - cb;
      int eend = min(cb + cn, oj1) - cb;
      int rl = max(eend - c, 0);
      int rmax = max(rl, __shfl_xor(rl, 16, 64));
      rmax = max(rmax, __shfl_xor(rmax, 32, 64));
      for (int r = 0; r < rmax; ++r) {
        bool act = c < eend;
        int i = act ? c : 0;
        int src = srcs_s[wv][i];
        float x0, x1, x2, x3;
        if (SRC_F32) {
          float4 xv = *(const float4*)((const float*)h_src +
                                       (size_t)src * 64 + fq * 4);
          x0 = xv.x; x1 = xv.y; x2 = xv.z; x3 = xv.w;
        } else {
          ushort4 u = *(const ushort4*)((const unsigned short*)h_src +
                                        (size_t)src * 64 + fq * 4);
          x0 = bf2f(u.x); x1 = bf2f(u.y); x2 = bf2f(u.z); x3 = bf2f(u.w);
        }
        if (!act) { x0 = 0.f; x1 = 0.f; x2 = 0.f; x3 = 0.f; }
        float4 lo = *(const float4*)&ew_s[wv][i * 8];
        float4 hi = *(const float4*)&ew_s[wv][i * 8 + 4];
        z[0][0] += lo.x * x0; z[0][1] += lo.x * x1; z[0][2] += lo.x * x2; z[0][3] += lo.x * x3;
        z[1][0] += lo.y * x0; z[1][1] += lo.y * x1; z[1][2] += lo.y * x2; z[1][3] += lo.y * x3;
        z[2][0] += lo.z * x0; z[2][1] += lo.z * x1; z[2][2] += lo.z * x2; z[2][3] += lo.z * x3;
        z[3][0] += lo.w * x0; z[3][1] += lo.w * x1; z[3][2] += lo.w * x2; z[3][3] += lo.w * x3;
        z[4][0] += hi.x * x0; z[4][1] += hi.x * x1; z[4][2] += hi.x * x2; z[4][3] += hi.x * x3;
        z[5][0] += hi.y * x0; z[5][1] += hi.y * x1; z[5][2] += hi.y * x2; z[5][3] += hi.y * x3;
        z[6][0] += hi.z * x0; z[6][1] += hi.z * x1; z[6][2] += hi.z * x2; z[6][3] += hi.z * x3;
        z[7][0] += hi.w * x0; z[7][1] += hi.w * x1; z[7][2] += hi.w * x2; z[7][3] += hi.w * x3;
        c += act ? 1 : 0;
      }
    }
  }

  // z -> LDS bf16: row = wv*4+sj, k' = (fq*4+fi)*8 + h (one b128 per fi)
  int row = wv * 4 + sj;
#pragma unroll
  for (int fi = 0; fi < 4; ++fi) {
    int4 pk;
    pk.x = ((int)f2bf(z[1][fi]) << 16) | f2bf(z[0][fi]);
    pk.y = ((int)f2bf(z[3][fi]) << 16) | f2bf(z[2][fi]);
    pk.z = ((int)f2bf(z[5][fi]) << 16) | f2bf(z[4][fi]);
    pk.w = ((int)f2bf(z[7][fi]) << 16) | f2bf(z[6][fi]);
    *(int4*)&Zl[row * 520 + (fq * 4 + fi) * 8] = pk;
  }
  __syncthreads();

  // MFMA epilogue: wave wv computes rows 0..15, cols wv*16..wv*16+15
  int arow = lane & 15;
  int kg = lane >> 4;
  f32x4 acc = {0.f, 0.f, 0.f, 0.f};
#pragma unroll
  for (int kt = 0; kt < 16; ++kt) {
    int kbase = kt * 32 + kg * 8;
    short8 a = *(const short8*)&Zl[arow * 520 + kbase];
    short8 b = *(const short8*)&Wrt[(size_t)(wv * 16 + arow) * 512 + kbase];
    acc = __builtin_amdgcn_mfma_f32_16x16x32_bf16(a, b, acc, 0, 0, 0);
  }

  int col = wv * 16 + arow;
  float o_r[4];
#pragma unroll
  for (int r = 0; r < 4; ++r) {
    int dloc = kg * 4 + r;
    int d = d0 + dloc;
    float o = 0.f;
    if (d < Nd) {
      float v = __bfloat162float(h_res[(size_t)d * 64 + col]) + 0.125f * acc[r];
      o = v > 0.f ? v : expm1f(v);
      out_f32[(size_t)d * 64 + col] = o;
    }
    o_r[r] = o;
  }

  if (WRITE_AJ) {
#pragma unroll
    for (int r = 0; r < 4; ++r) {
      int dloc = kg * 4 + r;
#pragma unroll
      for (int h = 0; h < 8; ++h) {
        float p = o_r[r] * vj_next[h * 64 + col];
        p += __shfl_xor(p, 1, 64);
        p += __shfl_xor(p, 2, 64);
        p += __shfl_xor(p, 4, 64);
        p += __shfl_xor(p, 8, 64);
        if (arow == 0) ajp[wv][dloc][h] = p;
      }
    }
    __syncthreads();
    if (t < 128) {
      int dloc = t >> 3, h = t & 7;
      int d = d0 + dloc;
      if (d < Nd) {
        float s = ajp[0][dloc][h] + ajp[1][dloc][h] + ajp[2][dloc][h] +
                  ajp[3][dloc][h];
        aj_next[(size_t)d * 8 + h] = s;
      }
    }
  }
}

// ---------------------------------------------------------------------------
extern "C" void kernel_launch(void* const* d_in, const int* in_sizes, int n_in,
                              void* d_out, int out_size, void* d_ws,
                              size_t ws_size, hipStream_t stream) {
  const void* op_nodes = d_in[0];
  const void* mc_nodes = d_in[1];
  const int* ei        = (const int*)d_in[2];
  const void* W_op     = d_in[3];
  const void* b_op     = d_in[4];
  const void* W_mc     = d_in[5];
  const void* b_mc     = d_in[6];
  const void* W_om     = d_in[7];
  const void* att_om   = d_in[8];
  const void* W_mo     = d_in[9];
  const void* att_mo   = d_in[10];

  int n_op = in_sizes[0] / 4;
  int n_mc = in_sizes[1] / 2;
  int E    = in_sizes[2] / 2;

  char* ws = (char*)d_ws;
  size_t off = 0;
  auto alloc = [&](size_t bytes) -> void* {
    void* p = ws + off;
    off = (off + bytes + 255) & ~(size_t)255;
    return p;
  };
  int* flags   = (int*)alloc(16);
  bf16* h_op   = (bf16*)alloc((size_t)n_op * 64 * 2);
  bf16* h_mc   = (bf16*)alloc((size_t)n_mc * 64 * 2);
  float* aj_op = (float*)alloc((size_t)n_op * 8 * 4);
  float* aj_mc = (float*)alloc((size_t)n_mc * 8 * 4);
  float* vj_om = (float*)alloc(512 * 4);
  float* vj_mo = (float*)alloc(512 * 4);
  bf16* Wrt_om = (bf16*)alloc(32768 * 2);
  bf16* Wrt_mo = (bf16*)alloc(32768 * 2);
  int* cnt1  = (int*)alloc((size_t)n_mc * 4);
  int* cnt2  = (int*)alloc((size_t)n_op * 4);
  int* offs1 = (int*)alloc((size_t)(n_mc + 1) * 4);
  int* cur1  = (int*)alloc((size_t)n_mc * 4);
  int* srcs1 = (int*)alloc((size_t)E * 4);
  int* offs2 = (int*)alloc((size_t)(n_op + 1) * 4);
  int* cur2  = (int*)alloc((size_t)n_op * 4);
  int* srcs2 = (int*)alloc((size_t)E * 4);
  int* bsum1 = (int*)alloc(256 * 4);
  int* bsum2 = (int*)alloc(256 * 4);

  float* out_op = (float*)d_out;
  float* out_mc = out_op + (size_t)n_op * 64;  // layer-1 result + layer-2 src

  init_kernel<<<512, 256, 0, stream>>>(ei, (const unsigned short*)op_nodes,
                                       flags, cnt1, n_mc, cnt2, n_op);

  prep_all<<<256, 256, 0, stream>>>(W_om, att_om, W_mo, att_mo, flags, vj_om,
                                    Wrt_om, vj_mo, Wrt_mo);

  int nbo = (n_op + 3) / 4, nbm = (n_mc + 3) / 4;
  node_all<<<nbo + nbm, 256, 0, stream>>>(op_nodes, W_op, b_op, mc_nodes, W_mc,
                                          b_mc, flags, vj_om, h_op, aj_op, h_mc,
                                          n_op, n_mc, nbo);

  count_edges<<<(E + 255) / 256, 256, 0, stream>>>(ei, E, flags, cnt1, cnt2);

  int nb1 = (n_mc + 2047) / 2048, nb2 = (n_op + 2047) / 2048;
  scan_bsum2<<<nb1 + nb2, 256, 0, stream>>>(cnt1, n_mc, nb1, cnt2, n_op, bsum1,
                                            bsum2);
  scan_write2<<<nb1 + nb2, 256, 0, stream>>>(cnt1, n_mc, nb1, bsum1, offs1,
                                             cur1, cnt2, n_op, nb2, bsum2,
                                             offs2, cur2);
  fill_edges<<<(E + 255) / 256, 256, 0, stream>>>(ei, E, flags, cur1, srcs1,
                                                  cur2, srcs2);

  // GAT1: op -> mc (writes out_mc f32 + aj_mc for layer 2)
  gat_fused<true, false><<<(n_mc + 15) / 16, 256, 0, stream>>>(
      n_mc, offs1, srcs1, aj_op, h_op, Wrt_om, h_mc, out_mc, vj_mo, aj_mc);
  // GAT2: mc -> op (src = layer-1 mc output, f32 in d_out)
  gat_fused<false, true><<<(n_op + 15) / 16, 256, 0, stream>>>(
      n_op, offs2, srcs2, aj_mc, out_mc, Wrt_mo, h_op, out_op,
      (const float*)nullptr, (float*)nullptr);
}

// Round 9
// 284.230 us; speedup vs baseline: 1.2291x; 1.1029x over previous
//
#include <hip/hip_runtime.h>
#include <hip/hip_bf16.h>

using bf16 = __hip_bfloat16;
typedef __attribute__((ext_vector_type(8))) short short8;
typedef __attribute__((ext_vector_type(4))) float f32x4;

__device__ __forceinline__ unsigned short f2bf(float f) {
  bf16 h = __float2bfloat16(f);
  return *reinterpret_cast<unsigned short*>(&h);
}
__device__ __forceinline__ float bf2f(unsigned short u) {
  return __uint_as_float(((unsigned)u) << 16);
}

__device__ __forceinline__ float loadf(const void* p, int i, int is_f32) {
  if (is_f32) return ((const float*)p)[i];
  return __bfloat162float(((const bf16*)p)[i]);
}

// ---------------------------------------------------------------------------
// init: zero counters (all blocks) + dtype detection (block 0)
// flags[0] = floats are f32, flags[1] = edges are int64
// ---------------------------------------------------------------------------
__global__ __launch_bounds__(256) void init_kernel(
    const int* __restrict__ ei, const unsigned short* __restrict__ x,
    int* __restrict__ flags, int* __restrict__ cnt1, int n1,
    int* __restrict__ cnt2, int n2) {
  int t = threadIdx.x;
  int g = blockIdx.x * 256 + t;
  int stride = gridDim.x * 256;
  for (int i = g; i < n1; i += stride) cnt1[i] = 0;
  for (int i = g; i < n2; i += stride) cnt2[i] = 0;
  if (blockIdx.x == 0) {
    __shared__ int red[256];
    int o = 0, big = 0;
    for (int i = t; i < 2048; i += 256) {
      o |= ei[2 * i + 1];
      float v = __uint_as_float(((unsigned)x[2 * i]) << 16);
      if (!(fabsf(v) < 1000.f)) big = 1;
    }
    red[t] = o;
    __syncthreads();
    for (int d = 128; d > 0; d >>= 1) {
      if (t < d) red[t] |= red[t + d];
      __syncthreads();
    }
    int o_all = red[0];
    __syncthreads();
    red[t] = big;
    __syncthreads();
    for (int d = 128; d > 0; d >>= 1) {
      if (t < d) red[t] |= red[t + d];
      __syncthreads();
    }
    if (t == 0) {
      flags[0] = red[0];
      flags[1] = (o_all == 0) ? 1 : 0;
    }
  }
}

__device__ __forceinline__ int edge_src(const int* ei, int E, int e, int i64) {
  return i64 ? ei[2 * e] : ei[e];
}
__device__ __forceinline__ int edge_dst(const int* ei, int E, int e, int i64) {
  return i64 ? ei[2 * E + 2 * e] : ei[E + e];
}

// ---------------------------------------------------------------------------
// node transform body: h = elu(x@W.T+b) -> bf16, optional a_j = h . v_j
// ---------------------------------------------------------------------------
template <int FIN>
__device__ __forceinline__ void node_body(
    const void* x, const void* W, const void* b, int is_f32,
    const float* vj, bf16* h_out, float* aj_out, int n) {
  int lane = threadIdx.x & 63;
  float acc = loadf(b, lane, is_f32);
#pragma unroll
  for (int f = 0; f < FIN; ++f)
    acc += loadf(x, n * FIN + f, is_f32) * loadf(W, lane * FIN + f, is_f32);
  float hv = acc > 0.f ? acc : expm1f(acc);
  h_out[(size_t)n * 64 + lane] = __float2bfloat16(hv);
  if (aj_out) {
#pragma unroll
    for (int hh = 0; hh < 8; ++hh) {
      float p = hv * vj[hh * 64 + lane];
#pragma unroll
      for (int o = 32; o >= 1; o >>= 1) p += __shfl_xor(p, o, 64);
      if (lane == 0) aj_out[(size_t)n * 8 + hh] = p;
    }
  }
}

// ---------------------------------------------------------------------------
// front: node(op) | node(mc) | prep(weights) | count(edges) in ONE launch
// ---------------------------------------------------------------------------
__global__ __launch_bounds__(256) void front_kernel(
    const void* __restrict__ x_op, const void* __restrict__ W_op,
    const void* __restrict__ b_op, const void* __restrict__ x_mc,
    const void* __restrict__ W_mc, const void* __restrict__ b_mc,
    const void* __restrict__ W1, const void* __restrict__ att1,
    const void* __restrict__ W2, const void* __restrict__ att2,
    const int* __restrict__ ei, const int* __restrict__ flags,
    float* __restrict__ vj1, bf16* __restrict__ Wrt1, float* __restrict__ vj2,
    bf16* __restrict__ Wrt2, bf16* __restrict__ h_op,
    float* __restrict__ aj_op, bf16* __restrict__ h_mc,
    int* __restrict__ cnt_dst, int* __restrict__ cnt_src, int n_op, int n_mc,
    int E, int nbo, int nbm) {
  int bid = blockIdx.x;
  int is_f32 = flags[0];
  if (bid < nbo) {
    int n = bid * 4 + (threadIdx.x >> 6);
    if (n < n_op) node_body<4>(x_op, W_op, b_op, is_f32, vj1, h_op, aj_op, n);
  } else if (bid < nbo + nbm) {
    int n = (bid - nbo) * 4 + (threadIdx.x >> 6);
    if (n < n_mc)
      node_body<2>(x_mc, W_mc, b_mc, is_f32, nullptr, h_mc, nullptr, n);
  } else if (bid < nbo + nbm + 256) {
    int pb = bid - nbo - nbm;
    int side = pb >= 128;
    const void* W = side ? W2 : W1;
    const void* att = side ? att2 : att1;
    float* vj = side ? vj2 : vj1;
    bf16* Wrt = side ? Wrt2 : Wrt1;
    int tt = (pb & 127) * 256 + threadIdx.x;
    if (tt < 32768) {
      int c = tt >> 9, k = tt & 511;
      int f = k >> 3, h = k & 7;
      Wrt[tt] = __float2bfloat16(loadf(W, ((h << 6) + c) * 64 + f, is_f32));
    }
    if (tt < 512) {
      int hh = tt >> 6, ff = tt & 63;
      float s = 0.f;
      for (int cc = 0; cc < 64; ++cc)
        s += loadf(att, hh * 128 + 64 + cc, is_f32) *
             loadf(W, ((hh << 6) + cc) * 64 + ff, is_f32);
      vj[tt] = s;
    }
  } else {
    int i64 = flags[1];
    int e = (bid - nbo - nbm - 256) * 256 + threadIdx.x;
    if (e < E) {
      atomicAdd(&cnt_dst[edge_dst(ei, E, e, i64)], 1);
      atomicAdd(&cnt_src[edge_src(ei, E, e, i64)], 1);
    }
  }
}

// ---------------------------------------------------------------------------
// CSR scan (2 kernels) + fill
// ---------------------------------------------------------------------------
__global__ __launch_bounds__(256) void scan_bsum2(
    const int* __restrict__ cnt1, int n1, int nb1, const int* __restrict__ cnt2,
    int n2, int* __restrict__ bsum1, int* __restrict__ bsum2) {
  __shared__ int red[256];
  int t = threadIdx.x;
  int side = (int)blockIdx.x >= nb1;
  const int* cnt = side ? cnt2 : cnt1;
  int n = side ? n2 : n1;
  int blk = side ? (blockIdx.x - nb1) : blockIdx.x;
  int base = blk * 2048 + t * 8;
  int s = 0;
#pragma unroll
  for (int i = 0; i < 8; ++i)
    if (base + i < n) s += cnt[base + i];
  red[t] = s;
  __syncthreads();
  for (int d = 128; d > 0; d >>= 1) {
    if (t < d) red[t] += red[t + d];
    __syncthreads();
  }
  if (t == 0) (side ? bsum2 : bsum1)[blk] = red[0];
}

__global__ __launch_bounds__(256) void scan_write2(
    const int* __restrict__ cnt1, int n1, int nb1,
    const int* __restrict__ bsum1, int* __restrict__ offs1,
    int* __restrict__ cur1, const int* __restrict__ cnt2, int n2, int nb2,
    const int* __restrict__ bsum2, int* __restrict__ offs2,
    int* __restrict__ cur2) {
  __shared__ int red[256];
  __shared__ int base_s;
  int t = threadIdx.x;
  int side = (int)blockIdx.x >= nb1;
  const int* cnt = side ? cnt2 : cnt1;
  const int* bsum = side ? bsum2 : bsum1;
  int* offs = side ? offs2 : offs1;
  int* cur = side ? cur2 : cur1;
  int n = side ? n2 : n1;
  int nb = side ? nb2 : nb1;
  int blk = side ? (blockIdx.x - nb1) : blockIdx.x;
  if (t == 0) {
    int b = 0;
    for (int i = 0; i < blk; ++i) b += bsum[i];
    base_s = b;
  }
  int base = blk * 2048 + t * 8;
  int c[8];
  int s = 0;
#pragma unroll
  for (int i = 0; i < 8; ++i) {
    c[i] = (base + i < n) ? cnt[base + i] : 0;
    s += c[i];
  }
  red[t] = s;
  __syncthreads();
  for (int d = 1; d < 256; d <<= 1) {
    int v = red[t];
    int add = (t >= d) ? red[t - d] : 0;
    __syncthreads();
    red[t] = v + add;
    __syncthreads();
  }
  int run = base_s + red[t] - s;
#pragma unroll
  for (int i = 0; i < 8; ++i) {
    if (base + i < n) {
      offs[base + i] = run;
      cur[base + i] = run;
      run += c[i];
    }
  }
  if (blk == nb - 1 && t == 255) offs[n] = base_s + red[255];
}

__global__ __launch_bounds__(256) void fill_edges(
    const int* __restrict__ ei, int E, const int* __restrict__ flags,
    int* __restrict__ cur1, int* __restrict__ srcs1, int* __restrict__ cur2,
    int* __restrict__ srcs2) {
  int i64 = flags[1];
  int e = blockIdx.x * blockDim.x + threadIdx.x;
  if (e < E) {
    int s = edge_src(ei, E, e, i64), d = edge_dst(ei, E, e, i64);
    int p = atomicAdd(&cur1[d], 1);
    srcs1[p] = s;
    int q = atomicAdd(&cur2[s], 1);
    srcs2[q] = d;
  }
}

// ---------------------------------------------------------------------------
// fused GAT v4: 16 dsts/block, block srcs staged in LDS once, quarter-wave
// gather with INDEPENDENT round indices (i = c0+r, no serial c++ chain),
// MFMA epilogue. Sources are bf16 (GAT1 writes h_mc bf16 for GAT2).
// ---------------------------------------------------------------------------
template <bool WRITE_AJ, bool WRITE_BF>
__global__ __launch_bounds__(256) void gat_fused(
    int Nd, const int* __restrict__ offs, const int* __restrict__ srcs,
    const float* __restrict__ aj, const bf16* __restrict__ h_src,
    const bf16* __restrict__ Wrt, const bf16* __restrict__ h_res,
    float* __restrict__ out_f32, bf16* __restrict__ out_bf,
    const float* __restrict__ vj_next, float* __restrict__ aj_next) {
  __shared__ __align__(16) unsigned short Zl[16 * 520];  // 16.3 KB
  __shared__ int srcs_s[512];                            // 2 KB
  __shared__ __align__(16) float ew_s[4][512];           // 8 KB
  __shared__ float mj_s[16][8], si_s[16][8];             // 1 KB
  __shared__ float ajp[4][16][8];                        // 2 KB

  int t = threadIdx.x;
  int wv = t >> 6, lane = t & 63;
  int d0 = blockIdx.x * 16;

  int gbeg = offs[min(d0, Nd)];
  int nE = offs[min(d0 + 16, Nd)] - gbeg;

  // ---- phase 1: stats (block-local edge coords; srcs from LDS) ----
  {
    int slot = t >> 4, h = (t >> 1) & 7, half = t & 1;
    int d = d0 + slot;
    int sbeg = 0, send = 0;
    if (d < Nd) {
      sbeg = offs[d] - gbeg;
      send = offs[d + 1] - gbeg;
    }
    float m = -INFINITY, s = 0.f;
    for (int sb = 0; sb < nE; sb += 512) {
      int sc = min(512, nE - sb);
      __syncthreads();
      for (int i = t; i < sc; i += 256) srcs_s[i] = srcs[gbeg + sb + i];
      __syncthreads();
      int lo = max(sbeg, sb), hi = min(send, sb + sc);
      float ml = -INFINITY;
#pragma unroll 4
      for (int e = lo + half; e < hi; e += 2)
        ml = fmaxf(ml, aj[(size_t)srcs_s[e - sb] * 8 + h]);
      float mn = fmaxf(m, ml);
      float sl = 0.f;
#pragma unroll 4
      for (int e = lo + half; e < hi; e += 2)
        sl += __expf(aj[(size_t)srcs_s[e - sb] * 8 + h] - mn);
      s = (s > 0.f ? s * __expf(m - mn) : 0.f) + sl;
      m = mn;
    }
    float mo = __shfl_xor(m, 1, 64);
    float so = __shfl_xor(s, 1, 64);
    float mn = fmaxf(m, mo);
    float sn = (s > 0.f ? s * __expf(m - mn) : 0.f) +
               (so > 0.f ? so * __expf(mo - mn) : 0.f);
    if (half == 0) {
      mj_s[slot][h] = mn;
      si_s[slot][h] = 1.f / (sn + 1e-16f);
    }
  }
  // wave wv wrote/reads only slots wv*4..wv*4+3 -> same-wave order, no barrier

  // ---- phase 2: gather, quarter-wave streams ----
  float z[8][4];
#pragma unroll
  for (int h = 0; h < 8; ++h)
#pragma unroll
    for (int f = 0; f < 4; ++f) z[h][f] = 0.f;

  int sj = lane >> 4;  // dst slot within wave
  int fq = lane & 15;  // feature quad
  int dlo = d0 + wv * 4;
  int wo0 = offs[min(dlo + 0, Nd)] - gbeg;
  int wo1 = offs[min(dlo + 1, Nd)] - gbeg;
  int wo2 = offs[min(dlo + 2, Nd)] - gbeg;
  int wo3 = offs[min(dlo + 3, Nd)] - gbeg;
  int wo4 = offs[min(dlo + 4, Nd)] - gbeg;
  int woj = sj == 0 ? wo0 : sj == 1 ? wo1 : sj == 2 ? wo2 : wo3;
  int woj1 = sj == 0 ? wo1 : sj == 1 ? wo2 : sj == 2 ? wo3 : wo4;

  bool multi = nE > 512;
  for (int sb = 0; sb < nE; sb += 512) {
    int sc = min(512, nE - sb);
    if (multi) {
      __syncthreads();
      for (int i = t; i < sc; i += 256) srcs_s[i] = srcs[gbeg + sb + i];
      __syncthreads();
    }
    int wlo = max(wo0, sb), whi = min(wo4, sb + sc);
    for (int cb = wlo; cb < whi; cb += 64) {
      int cn = min(64, whi - cb);
      // normalized weights for this chunk -> LDS (wave-local)
      for (int i = lane; i < cn * 8; i += 64) {
        int e = i >> 3, hh = i & 7;
        int ge = cb + e;
        int j = (ge >= wo1) + (ge >= wo2) + (ge >= wo3);
        int sl2 = wv * 4 + j;
        float a = aj[(size_t)srcs_s[ge - sb] * 8 + hh];
        ew_s[wv][i] = __expf(a - mj_s[sl2][hh]) * si_s[sl2][hh];
      }
      // rounds with independent indices (no serial chain)
      int c0 = max(cb, woj) - cb;
      int e1 = min(cb + cn, woj1) - cb;
      int rl = max(e1 - c0, 0);
      int rmax = max(rl, __shfl_xor(rl, 16, 64));
      rmax = max(rmax, __shfl_xor(rmax, 32, 64));
      for (int r = 0; r < rmax; ++r) {
        bool act = r < rl;
        int i2 = act ? (c0 + r) : 0;
        int src = srcs_s[cb - sb + i2];
        ushort4 u = *(const ushort4*)((const unsigned short*)h_src +
                                      (size_t)src * 64 + fq * 4);
        float x0 = bf2f(u.x), x1 = bf2f(u.y), x2 = bf2f(u.z), x3 = bf2f(u.w);
        if (!act) {
          x0 = 0.f; x1 = 0.f; x2 = 0.f; x3 = 0.f;
        }
        float4 lo4 = *(const float4*)&ew_s[wv][i2 * 8];
        float4 hi4 = *(const float4*)&ew_s[wv][i2 * 8 + 4];
        z[0][0] += lo4.x * x0; z[0][1] += lo4.x * x1; z[0][2] += lo4.x * x2; z[0][3] += lo4.x * x3;
        z[1][0] += lo4.y * x0; z[1][1] += lo4.y * x1; z[1][2] += lo4.y * x2; z[1][3] += lo4.y * x3;
        z[2][0] += lo4.z * x0; z[2][1] += lo4.z * x1; z[2][2] += lo4.z * x2; z[2][3] += lo4.z * x3;
        z[3][0] += lo4.w * x0; z[3][1] += lo4.w * x1; z[3][2] += lo4.w * x2; z[3][3] += lo4.w * x3;
        z[4][0] += hi4.x * x0; z[4][1] += hi4.x * x1; z[4][2] += hi4.x * x2; z[4][3] += hi4.x * x3;
        z[5][0] += hi4.y * x0; z[5][1] += hi4.y * x1; z[5][2] += hi4.y * x2; z[5][3] += hi4.y * x3;
        z[6][0] += hi4.z * x0; z[6][1] += hi4.z * x1; z[6][2] += hi4.z * x2; z[6][3] += hi4.z * x3;
        z[7][0] += hi4.w * x0; z[7][1] += hi4.w * x1; z[7][2] += hi4.w * x2; z[7][3] += hi4.w * x3;
      }
    }
  }

  // z -> Zl bf16: row = wv*4+sj, k' = (fq*4+fi)*8 + h
  int row = wv * 4 + sj;
#pragma unroll
  for (int fi = 0; fi < 4; ++fi) {
    int4 pk;
    pk.x = ((int)f2bf(z[1][fi]) << 16) | f2bf(z[0][fi]);
    pk.y = ((int)f2bf(z[3][fi]) << 16) | f2bf(z[2][fi]);
    pk.z = ((int)f2bf(z[5][fi]) << 16) | f2bf(z[4][fi]);
    pk.w = ((int)f2bf(z[7][fi]) << 16) | f2bf(z[6][fi]);
    *(int4*)&Zl[row * 520 + (fq * 4 + fi) * 8] = pk;
  }
  __syncthreads();

  // MFMA epilogue: wave wv computes rows 0..15, cols wv*16..wv*16+15
  int arow = lane & 15;
  int kg = lane >> 4;
  f32x4 acc = {0.f, 0.f, 0.f, 0.f};
#pragma unroll
  for (int kt = 0; kt < 16; ++kt) {
    int kbase = kt * 32 + kg * 8;
    short8 a = *(const short8*)&Zl[arow * 520 + kbase];
    short8 b = *(const short8*)&Wrt[(size_t)(wv * 16 + arow) * 512 + kbase];
    acc = __builtin_amdgcn_mfma_f32_16x16x32_bf16(a, b, acc, 0, 0, 0);
  }

  int col = wv * 16 + arow;
  float o_r[4];
#pragma unroll
  for (int r = 0; r < 4; ++r) {
    int dloc = kg * 4 + r;
    int d = d0 + dloc;
    float o = 0.f;
    if (d < Nd) {
      float v = __bfloat162float(h_res[(size_t)d * 64 + col]) + 0.125f * acc[r];
      o = v > 0.f ? v : expm1f(v);
      out_f32[(size_t)d * 64 + col] = o;
      if (WRITE_BF) out_bf[(size_t)d * 64 + col] = __float2bfloat16(o);
    }
    o_r[r] = o;
  }

  if (WRITE_AJ) {
#pragma unroll
    for (int r = 0; r < 4; ++r) {
      int dloc = kg * 4 + r;
#pragma unroll
      for (int h = 0; h < 8; ++h) {
        float p = o_r[r] * vj_next[h * 64 + col];
        p += __shfl_xor(p, 1, 64);
        p += __shfl_xor(p, 2, 64);
        p += __shfl_xor(p, 4, 64);
        p += __shfl_xor(p, 8, 64);
        if (arow == 0) ajp[wv][dloc][h] = p;
      }
    }
    __syncthreads();
    if (t < 128) {
      int dloc = t >> 3, h = t & 7;
      int d = d0 + dloc;
      if (d < Nd) {
        float s = ajp[0][dloc][h] + ajp[1][dloc][h] + ajp[2][dloc][h] +
                  ajp[3][dloc][h];
        aj_next[(size_t)d * 8 + h] = s;
      }
    }
  }
}

// ---------------------------------------------------------------------------
extern "C" void kernel_launch(void* const* d_in, const int* in_sizes, int n_in,
                              void* d_out, int out_size, void* d_ws,
                              size_t ws_size, hipStream_t stream) {
  const void* op_nodes = d_in[0];
  const void* mc_nodes = d_in[1];
  const int* ei        = (const int*)d_in[2];
  const void* W_op     = d_in[3];
  const void* b_op     = d_in[4];
  const void* W_mc     = d_in[5];
  const void* b_mc     = d_in[6];
  const void* W_om     = d_in[7];
  const void* att_om   = d_in[8];
  const void* W_mo     = d_in[9];
  const void* att_mo   = d_in[10];

  int n_op = in_sizes[0] / 4;
  int n_mc = in_sizes[1] / 2;
  int E    = in_sizes[2] / 2;

  char* ws = (char*)d_ws;
  size_t off = 0;
  auto alloc = [&](size_t bytes) -> void* {
    void* p = ws + off;
    off = (off + bytes + 255) & ~(size_t)255;
    return p;
  };
  int* flags   = (int*)alloc(16);
  bf16* h_op   = (bf16*)alloc((size_t)n_op * 64 * 2);
  bf16* h_mc   = (bf16*)alloc((size_t)n_mc * 64 * 2);
  bf16* h_mc2  = (bf16*)alloc((size_t)n_mc * 64 * 2);
  float* aj_op = (float*)alloc((size_t)n_op * 8 * 4);
  float* aj_mc = (float*)alloc((size_t)n_mc * 8 * 4);
  float* vj_om = (float*)alloc(512 * 4);
  float* vj_mo = (float*)alloc(512 * 4);
  bf16* Wrt_om = (bf16*)alloc(32768 * 2);
  bf16* Wrt_mo = (bf16*)alloc(32768 * 2);
  int* cnt1  = (int*)alloc((size_t)n_mc * 4);
  int* cnt2  = (int*)alloc((size_t)n_op * 4);
  int* offs1 = (int*)alloc((size_t)(n_mc + 1) * 4);
  int* cur1  = (int*)alloc((size_t)n_mc * 4);
  int* srcs1 = (int*)alloc((size_t)E * 4);
  int* offs2 = (int*)alloc((size_t)(n_op + 1) * 4);
  int* cur2  = (int*)alloc((size_t)n_op * 4);
  int* srcs2 = (int*)alloc((size_t)E * 4);
  int* bsum1 = (int*)alloc(256 * 4);
  int* bsum2 = (int*)alloc(256 * 4);

  float* out_op = (float*)d_out;
  float* out_mc = out_op + (size_t)n_op * 64;

  init_kernel<<<512, 256, 0, stream>>>(ei, (const unsigned short*)op_nodes,
                                       flags, cnt1, n_mc, cnt2, n_op);

  int nbo = (n_op + 3) / 4, nbm = (n_mc + 3) / 4;
  int nbe = (E + 255) / 256;
  front_kernel<<<nbo + nbm + 256 + nbe, 256, 0, stream>>>(
      op_nodes, W_op, b_op, mc_nodes, W_mc, b_mc, W_om, att_om, W_mo, att_mo,
      ei, flags, vj_om, Wrt_om, vj_mo, Wrt_mo, h_op, aj_op, h_mc, cnt1, cnt2,
      n_op, n_mc, E, nbo, nbm);

  int nb1 = (n_mc + 2047) / 2048, nb2 = (n_op + 2047) / 2048;
  scan_bsum2<<<nb1 + nb2, 256, 0, stream>>>(cnt1, n_mc, nb1, cnt2, n_op, bsum1,
                                            bsum2);
  scan_write2<<<nb1 + nb2, 256, 0, stream>>>(cnt1, n_mc, nb1, bsum1, offs1,
                                             cur1, cnt2, n_op, nb2, bsum2,
                                             offs2, cur2);
  fill_edges<<<nbe, 256, 0, stream>>>(ei, E, flags, cur1, srcs1, cur2, srcs2);

  // GAT1: op -> mc (writes out_mc f32 + h_mc2 bf16 + aj_mc)
  gat_fused<true, true><<<(n_mc + 15) / 16, 256, 0, stream>>>(
      n_mc, offs1, srcs1, aj_op, h_op, Wrt_om, h_mc, out_mc, h_mc2, vj_mo,
      aj_mc);
  // GAT2: mc -> op (src = h_mc2 bf16)
  gat_fused<false, false><<<(n_op + 15) / 16, 256, 0, stream>>>(
      n_op, offs2, srcs2, aj_mc, h_mc2, Wrt_mo, h_op, out_op, (bf16*)nullptr,
      (const float*)nullptr, (float*)nullptr);
}

// Round 10
// 240.158 us; speedup vs baseline: 1.4547x; 1.1835x over previous
//
#include <hip/hip_runtime.h>
#include <hip/hip_bf16.h>

using bf16 = __hip_bfloat16;
typedef __attribute__((ext_vector_type(8))) short short8;
typedef __attribute__((ext_vector_type(4))) float f32x4;

__device__ __forceinline__ unsigned short f2bf(float f) {
  bf16 h = __float2bfloat16(f);
  return *reinterpret_cast<unsigned short*>(&h);
}
__device__ __forceinline__ float bf2f(unsigned short u) {
  return __uint_as_float(((unsigned)u) << 16);
}

__device__ __forceinline__ float loadf(const void* p, int i, int is_f32) {
  if (is_f32) return ((const float*)p)[i];
  return __bfloat162float(((const bf16*)p)[i]);
}

// ---------------------------------------------------------------------------
// init: zero counters (all blocks) + dtype detection (block 0)
// flags[0] = floats are f32, flags[1] = edges are int64
// ---------------------------------------------------------------------------
__global__ __launch_bounds__(256) void init_kernel(
    const int* __restrict__ ei, const unsigned short* __restrict__ x,
    int* __restrict__ flags, int* __restrict__ cnt1, int n1,
    int* __restrict__ cnt2, int n2) {
  int t = threadIdx.x;
  int g = blockIdx.x * 256 + t;
  int stride = gridDim.x * 256;
  for (int i = g; i < n1; i += stride) cnt1[i] = 0;
  for (int i = g; i < n2; i += stride) cnt2[i] = 0;
  if (blockIdx.x == 0) {
    __shared__ int red[256];
    int o = 0, big = 0;
    for (int i = t; i < 2048; i += 256) {
      o |= ei[2 * i + 1];
      float v = __uint_as_float(((unsigned)x[2 * i]) << 16);
      if (!(fabsf(v) < 1000.f)) big = 1;
    }
    red[t] = o;
    __syncthreads();
    for (int d = 128; d > 0; d >>= 1) {
      if (t < d) red[t] |= red[t + d];
      __syncthreads();
    }
    int o_all = red[0];
    __syncthreads();
    red[t] = big;
    __syncthreads();
    for (int d = 128; d > 0; d >>= 1) {
      if (t < d) red[t] |= red[t + d];
      __syncthreads();
    }
    if (t == 0) {
      flags[0] = red[0];
      flags[1] = (o_all == 0) ? 1 : 0;
    }
  }
}

__device__ __forceinline__ int edge_src(const int* ei, int E, int e, int i64) {
  return i64 ? ei[2 * e] : ei[e];
}
__device__ __forceinline__ int edge_dst(const int* ei, int E, int e, int i64) {
  return i64 ? ei[2 * E + 2 * e] : ei[E + e];
}

// ---------------------------------------------------------------------------
// node transform body: h = elu(x@W.T+b) -> bf16; op side also writes
// ea[n][h] = exp(h . v_j[h]) via 10-shuffle multi-value butterfly
// (fold heads into lane bits: xor4,xor2,xor1 with send/keep, then xor8,16,32;
//  lane l in 0..7 ends holding head l = 4*bit2+2*bit1+bit0 of l)
// ---------------------------------------------------------------------------
template <int FIN>
__device__ __forceinline__ void node_body(
    const void* x, const void* W, const void* b, int is_f32,
    const float* vj, bf16* h_out, float* ea_out, int n) {
  int lane = threadIdx.x & 63;
  float acc = loadf(b, lane, is_f32);
#pragma unroll
  for (int f = 0; f < FIN; ++f)
    acc += loadf(x, n * FIN + f, is_f32) * loadf(W, lane * FIN + f, is_f32);
  float hv = acc > 0.f ? acc : expm1f(acc);
  h_out[(size_t)n * 64 + lane] = __float2bfloat16(hv);
  if (ea_out) {
    float p[8];
#pragma unroll
    for (int h = 0; h < 8; ++h) p[h] = hv * vj[h * 64 + lane];
#pragma unroll
    for (int i = 0; i < 4; ++i) {
      float send = (lane & 4) ? p[i] : p[i + 4];
      float keep = (lane & 4) ? p[i + 4] : p[i];
      p[i] = keep + __shfl_xor(send, 4, 64);
    }
#pragma unroll
    for (int i = 0; i < 2; ++i) {
      float send = (lane & 2) ? p[i] : p[i + 2];
      float keep = (lane & 2) ? p[i + 2] : p[i];
      p[i] = keep + __shfl_xor(send, 2, 64);
    }
    {
      float send = (lane & 1) ? p[0] : p[1];
      float keep = (lane & 1) ? p[1] : p[0];
      p[0] = keep + __shfl_xor(send, 1, 64);
    }
    p[0] += __shfl_xor(p[0], 8, 64);
    p[0] += __shfl_xor(p[0], 16, 64);
    p[0] += __shfl_xor(p[0], 32, 64);
    if (lane < 8) ea_out[(size_t)n * 8 + lane] = __expf(p[0]);
  }
}

// ---------------------------------------------------------------------------
// front: node(op) | node(mc) | prep(weights) | count(edges) in ONE launch
// ---------------------------------------------------------------------------
__global__ __launch_bounds__(256) void front_kernel(
    const void* __restrict__ x_op, const void* __restrict__ W_op,
    const void* __restrict__ b_op, const void* __restrict__ x_mc,
    const void* __restrict__ W_mc, const void* __restrict__ b_mc,
    const void* __restrict__ W1, const void* __restrict__ att1,
    const void* __restrict__ W2, const void* __restrict__ att2,
    const int* __restrict__ ei, const int* __restrict__ flags,
    float* __restrict__ vj1, bf16* __restrict__ Wrt1, float* __restrict__ vj2,
    bf16* __restrict__ Wrt2, bf16* __restrict__ h_op,
    float* __restrict__ ea_op, bf16* __restrict__ h_mc,
    int* __restrict__ cnt_dst, int* __restrict__ cnt_src, int n_op, int n_mc,
    int E, int nbo, int nbm) {
  int bid = blockIdx.x;
  int is_f32 = flags[0];
  if (bid < nbo) {
    int n = bid * 4 + (threadIdx.x >> 6);
    if (n < n_op) node_body<4>(x_op, W_op, b_op, is_f32, vj1, h_op, ea_op, n);
  } else if (bid < nbo + nbm) {
    int n = (bid - nbo) * 4 + (threadIdx.x >> 6);
    if (n < n_mc)
      node_body<2>(x_mc, W_mc, b_mc, is_f32, nullptr, h_mc, nullptr, n);
  } else if (bid < nbo + nbm + 256) {
    int pb = bid - nbo - nbm;
    int side = pb >= 128;
    const void* W = side ? W2 : W1;
    const void* att = side ? att2 : att1;
    float* vj = side ? vj2 : vj1;
    bf16* Wrt = side ? Wrt2 : Wrt1;
    int tt = (pb & 127) * 256 + threadIdx.x;
    if (tt < 32768) {
      int c = tt >> 9, k = tt & 511;
      int f = k >> 3, h = k & 7;
      Wrt[tt] = __float2bfloat16(loadf(W, ((h << 6) + c) * 64 + f, is_f32));
    }
    if (tt < 512) {
      int hh = tt >> 6, ff = tt & 63;
      float s = 0.f;
      for (int cc = 0; cc < 64; ++cc)
        s += loadf(att, hh * 128 + 64 + cc, is_f32) *
             loadf(W, ((hh << 6) + cc) * 64 + ff, is_f32);
      vj[tt] = s;
    }
  } else {
    int i64 = flags[1];
    int e = (bid - nbo - nbm - 256) * 256 + threadIdx.x;
    if (e < E) {
      atomicAdd(&cnt_dst[edge_dst(ei, E, e, i64)], 1);
      atomicAdd(&cnt_src[edge_src(ei, E, e, i64)], 1);
    }
  }
}

// ---------------------------------------------------------------------------
// CSR scan (2 kernels) + fill
// ---------------------------------------------------------------------------
__global__ __launch_bounds__(256) void scan_bsum2(
    const int* __restrict__ cnt1, int n1, int nb1, const int* __restrict__ cnt2,
    int n2, int* __restrict__ bsum1, int* __restrict__ bsum2) {
  __shared__ int red[256];
  int t = threadIdx.x;
  int side = (int)blockIdx.x >= nb1;
  const int* cnt = side ? cnt2 : cnt1;
  int n = side ? n2 : n1;
  int blk = side ? (blockIdx.x - nb1) : blockIdx.x;
  int base = blk * 2048 + t * 8;
  int s = 0;
#pragma unroll
  for (int i = 0; i < 8; ++i)
    if (base + i < n) s += cnt[base + i];
  red[t] = s;
  __syncthreads();
  for (int d = 128; d > 0; d >>= 1) {
    if (t < d) red[t] += red[t + d];
    __syncthreads();
  }
  if (t == 0) (side ? bsum2 : bsum1)[blk] = red[0];
}

__global__ __launch_bounds__(256) void scan_write2(
    const int* __restrict__ cnt1, int n1, int nb1,
    const int* __restrict__ bsum1, int* __restrict__ offs1,
    int* __restrict__ cur1, const int* __restrict__ cnt2, int n2, int nb2,
    const int* __restrict__ bsum2, int* __restrict__ offs2,
    int* __restrict__ cur2) {
  __shared__ int red[256];
  __shared__ int base_s;
  int t = threadIdx.x;
  int side = (int)blockIdx.x >= nb1;
  const int* cnt = side ? cnt2 : cnt1;
  const int* bsum = side ? bsum2 : bsum1;
  int* offs = side ? offs2 : offs1;
  int* cur = side ? cur2 : cur1;
  int n = side ? n2 : n1;
  int nb = side ? nb2 : nb1;
  int blk = side ? (blockIdx.x - nb1) : blockIdx.x;
  if (t == 0) {
    int b = 0;
    for (int i = 0; i < blk; ++i) b += bsum[i];
    base_s = b;
  }
  int base = blk * 2048 + t * 8;
  int c[8];
  int s = 0;
#pragma unroll
  for (int i = 0; i < 8; ++i) {
    c[i] = (base + i < n) ? cnt[base + i] : 0;
    s += c[i];
  }
  red[t] = s;
  __syncthreads();
  for (int d = 1; d < 256; d <<= 1) {
    int v = red[t];
    int add = (t >= d) ? red[t - d] : 0;
    __syncthreads();
    red[t] = v + add;
    __syncthreads();
  }
  int run = base_s + red[t] - s;
#pragma unroll
  for (int i = 0; i < 8; ++i) {
    if (base + i < n) {
      offs[base + i] = run;
      cur[base + i] = run;
      run += c[i];
    }
  }
  if (blk == nb - 1 && t == 255) offs[n] = base_s + red[255];
}

__global__ __launch_bounds__(256) void fill_edges(
    const int* __restrict__ ei, int E, const int* __restrict__ flags,
    int* __restrict__ cur1, int* __restrict__ srcs1, int* __restrict__ cur2,
    int* __restrict__ srcs2) {
  int i64 = flags[1];
  int e = blockIdx.x * blockDim.x + threadIdx.x;
  if (e < E) {
    int s = edge_src(ei, E, e, i64), d = edge_dst(ei, E, e, i64);
    int p = atomicAdd(&cur1[d], 1);
    srcs1[p] = s;
    int q = atomicAdd(&cur2[s], 1);
    srcs2[q] = d;
  }
}

// ---------------------------------------------------------------------------
// fused GAT v5 (statless): 16 dsts/block, 4 dsts/wave, quarter-wave streams.
// Node stage pre-exponentiated ea = exp(a_j) (softmax shift-invariance; a_j
// bounded ~|5| with 0.1-scale weights -> no overflow; ref eps=1e-16 is <=
// 1e-16 relative). Per chunk: stage srcs + ea rows (zero-padded slot at cn),
// then rounds accumulate BOTH z[h][f] and s[h]; 1/s folded into bf16 pack.
// No barriers until the MFMA epilogue.
// ---------------------------------------------------------------------------
template <bool WRITE_AJ, bool WRITE_BF>
__global__ __launch_bounds__(256) void gat_fused(
    int Nd, const int* __restrict__ offs, const int* __restrict__ srcs,
    const float* __restrict__ ea, const bf16* __restrict__ h_src,
    const bf16* __restrict__ Wrt, const bf16* __restrict__ h_res,
    float* __restrict__ out_f32, bf16* __restrict__ out_bf,
    const float* __restrict__ vj_next, float* __restrict__ ea_next) {
  __shared__ __align__(16) unsigned short Zl[16 * 520];  // 16.3 KB
  __shared__ int srcs_sw[4][65];                         // 1 KB
  __shared__ __align__(16) float ew_s[4][520];           // 8.1 KB
  __shared__ float ajp[4][16][8];                        // 2 KB

  int t = threadIdx.x;
  int wv = t >> 6, lane = t & 63;
  int d0 = blockIdx.x * 16;
  int sj = lane >> 4;  // dst slot within wave
  int fq = lane & 15;  // feature quad

  int dlo = d0 + wv * 4;
  int wo0 = offs[min(dlo + 0, Nd)];
  int wo1 = offs[min(dlo + 1, Nd)];
  int wo2 = offs[min(dlo + 2, Nd)];
  int wo3 = offs[min(dlo + 3, Nd)];
  int wo4 = offs[min(dlo + 4, Nd)];
  int woj = sj == 0 ? wo0 : sj == 1 ? wo1 : sj == 2 ? wo2 : wo3;
  int woj1 = sj == 0 ? wo1 : sj == 1 ? wo2 : sj == 2 ? wo3 : wo4;

  float z[8][4];  // [head][feat-in-quad]
#pragma unroll
  for (int h = 0; h < 8; ++h)
#pragma unroll
    for (int f = 0; f < 4; ++f) z[h][f] = 0.f;
  float s8[8];
#pragma unroll
  for (int h = 0; h < 8; ++h) s8[h] = 0.f;

  for (int cb = wo0; cb < wo4; cb += 64) {
    int cn = min(64, wo4 - cb);
    // stage srcs (+ zero slot at cn) and ea rows (+ zero row at cn)
    for (int i = lane; i < cn + 1; i += 64)
      srcs_sw[wv][i] = (i < cn) ? srcs[cb + i] : 0;
    for (int i = lane; i < (cn + 1) * 8; i += 64) {
      int e = i >> 3;
      ew_s[wv][i] =
          (e < cn) ? ea[(size_t)srcs_sw[wv][e] * 8 + (i & 7)] : 0.f;
    }
    // rounds: independent indices; inactive rounds hit the zero row
    int c0 = max(cb, woj) - cb;
    int e1 = min(cb + cn, woj1) - cb;
    int rl = max(e1 - c0, 0);
    int rmax = max(rl, __shfl_xor(rl, 16, 64));
    rmax = max(rmax, __shfl_xor(rmax, 32, 64));
    for (int r = 0; r < rmax; ++r) {
      int i2 = (r < rl) ? (c0 + r) : cn;
      int src = srcs_sw[wv][i2];
      ushort4 u = *(const ushort4*)((const unsigned short*)h_src +
                                    (size_t)src * 64 + fq * 4);
      float x0 = bf2f(u.x), x1 = bf2f(u.y), x2 = bf2f(u.z), x3 = bf2f(u.w);
      float4 lo4 = *(const float4*)&ew_s[wv][i2 * 8];
      float4 hi4 = *(const float4*)&ew_s[wv][i2 * 8 + 4];
      z[0][0] += lo4.x * x0; z[0][1] += lo4.x * x1; z[0][2] += lo4.x * x2; z[0][3] += lo4.x * x3;
      z[1][0] += lo4.y * x0; z[1][1] += lo4.y * x1; z[1][2] += lo4.y * x2; z[1][3] += lo4.y * x3;
      z[2][0] += lo4.z * x0; z[2][1] += lo4.z * x1; z[2][2] += lo4.z * x2; z[2][3] += lo4.z * x3;
      z[3][0] += lo4.w * x0; z[3][1] += lo4.w * x1; z[3][2] += lo4.w * x2; z[3][3] += lo4.w * x3;
      z[4][0] += hi4.x * x0; z[4][1] += hi4.x * x1; z[4][2] += hi4.x * x2; z[4][3] += hi4.x * x3;
      z[5][0] += hi4.y * x0; z[5][1] += hi4.y * x1; z[5][2] += hi4.y * x2; z[5][3] += hi4.y * x3;
      z[6][0] += hi4.z * x0; z[6][1] += hi4.z * x1; z[6][2] += hi4.z * x2; z[6][3] += hi4.z * x3;
      z[7][0] += hi4.w * x0; z[7][1] += hi4.w * x1; z[7][2] += hi4.w * x2; z[7][3] += hi4.w * x3;
      s8[0] += lo4.x; s8[1] += lo4.y; s8[2] += lo4.z; s8[3] += lo4.w;
      s8[4] += hi4.x; s8[5] += hi4.y; s8[6] += hi4.z; s8[7] += hi4.w;
    }
  }

  // normalize at pack time: z * (1/s)  -> Zl bf16, row = wv*4+sj
  float si[8];
#pragma unroll
  for (int h = 0; h < 8; ++h) si[h] = s8[h] > 0.f ? 1.f / s8[h] : 0.f;
  int row = wv * 4 + sj;
#pragma unroll
  for (int fi = 0; fi < 4; ++fi) {
    int4 pk;
    pk.x = ((int)f2bf(z[1][fi] * si[1]) << 16) | f2bf(z[0][fi] * si[0]);
    pk.y = ((int)f2bf(z[3][fi] * si[3]) << 16) | f2bf(z[2][fi] * si[2]);
    pk.z = ((int)f2bf(z[5][fi] * si[5]) << 16) | f2bf(z[4][fi] * si[4]);
    pk.w = ((int)f2bf(z[7][fi] * si[7]) << 16) | f2bf(z[6][fi] * si[6]);
    *(int4*)&Zl[row * 520 + (fq * 4 + fi) * 8] = pk;
  }
  __syncthreads();

  // MFMA epilogue: wave wv computes rows 0..15, cols wv*16..wv*16+15
  int arow = lane & 15;
  int kg = lane >> 4;
  f32x4 acc = {0.f, 0.f, 0.f, 0.f};
#pragma unroll
  for (int kt = 0; kt < 16; ++kt) {
    int kbase = kt * 32 + kg * 8;
    short8 a = *(const short8*)&Zl[arow * 520 + kbase];
    short8 b = *(const short8*)&Wrt[(size_t)(wv * 16 + arow) * 512 + kbase];
    acc = __builtin_amdgcn_mfma_f32_16x16x32_bf16(a, b, acc, 0, 0, 0);
  }

  int col = wv * 16 + arow;
  float o_r[4];
#pragma unroll
  for (int r = 0; r < 4; ++r) {
    int dloc = kg * 4 + r;
    int d = d0 + dloc;
    float o = 0.f;
    if (d < Nd) {
      float v = __bfloat162float(h_res[(size_t)d * 64 + col]) + 0.125f * acc[r];
      o = v > 0.f ? v : expm1f(v);
      out_f32[(size_t)d * 64 + col] = o;
      if (WRITE_BF) out_bf[(size_t)d * 64 + col] = __float2bfloat16(o);
    }
    o_r[r] = o;
  }

  if (WRITE_AJ) {
    // per r: multi-value butterfly over the 16 arow lanes (8 shfl each)
#pragma unroll
    for (int r = 0; r < 4; ++r) {
      int dloc = kg * 4 + r;
      float p[8];
#pragma unroll
      for (int h = 0; h < 8; ++h) p[h] = o_r[r] * vj_next[h * 64 + col];
#pragma unroll
      for (int i = 0; i < 4; ++i) {
        float send = (arow & 4) ? p[i] : p[i + 4];
        float keep = (arow & 4) ? p[i + 4] : p[i];
        p[i] = keep + __shfl_xor(send, 4, 64);
      }
#pragma unroll
      for (int i = 0; i < 2; ++i) {
        float send = (arow & 2) ? p[i] : p[i + 2];
        float keep = (arow & 2) ? p[i + 2] : p[i];
        p[i] = keep + __shfl_xor(send, 2, 64);
      }
      {
        float send = (arow & 1) ? p[0] : p[1];
        float keep = (arow & 1) ? p[1] : p[0];
        p[0] = keep + __shfl_xor(send, 1, 64);
      }
      p[0] += __shfl_xor(p[0], 8, 64);
      if (arow < 8) ajp[wv][dloc][arow] = p[0];
    }
    __syncthreads();
    if (t < 128) {
      int dloc = t >> 3, h = t & 7;
      int d = d0 + dloc;
      if (d < Nd) {
        float s = ajp[0][dloc][h] + ajp[1][dloc][h] + ajp[2][dloc][h] +
                  ajp[3][dloc][h];
        ea_next[(size_t)d * 8 + h] = __expf(s);
      }
    }
  }
}

// ---------------------------------------------------------------------------
extern "C" void kernel_launch(void* const* d_in, const int* in_sizes, int n_in,
                              void* d_out, int out_size, void* d_ws,
                              size_t ws_size, hipStream_t stream) {
  const void* op_nodes = d_in[0];
  const void* mc_nodes = d_in[1];
  const int* ei        = (const int*)d_in[2];
  const void* W_op     = d_in[3];
  const void* b_op     = d_in[4];
  const void* W_mc     = d_in[5];
  const void* b_mc     = d_in[6];
  const void* W_om     = d_in[7];
  const void* att_om   = d_in[8];
  const void* W_mo     = d_in[9];
  const void* att_mo   = d_in[10];

  int n_op = in_sizes[0] / 4;
  int n_mc = in_sizes[1] / 2;
  int E    = in_sizes[2] / 2;

  char* ws = (char*)d_ws;
  size_t off = 0;
  auto alloc = [&](size_t bytes) -> void* {
    void* p = ws + off;
    off = (off + bytes + 255) & ~(size_t)255;
    return p;
  };
  int* flags   = (int*)alloc(16);
  bf16* h_op   = (bf16*)alloc((size_t)n_op * 64 * 2);
  bf16* h_mc   = (bf16*)alloc((size_t)n_mc * 64 * 2);
  bf16* h_mc2  = (bf16*)alloc((size_t)n_mc * 64 * 2);
  float* ea_op = (float*)alloc((size_t)n_op * 8 * 4);
  float* ea_mc = (float*)alloc((size_t)n_mc * 8 * 4);
  float* vj_om = (float*)alloc(512 * 4);
  float* vj_mo = (float*)alloc(512 * 4);
  bf16* Wrt_om = (bf16*)alloc(32768 * 2);
  bf16* Wrt_mo = (bf16*)alloc(32768 * 2);
  int* cnt1  = (int*)alloc((size_t)n_mc * 4);
  int* cnt2  = (int*)alloc((size_t)n_op * 4);
  int* offs1 = (int*)alloc((size_t)(n_mc + 1) * 4);
  int* cur1  = (int*)alloc((size_t)n_mc * 4);
  int* srcs1 = (int*)alloc((size_t)E * 4);
  int* offs2 = (int*)alloc((size_t)(n_op + 1) * 4);
  int* cur2  = (int*)alloc((size_t)n_op * 4);
  int* srcs2 = (int*)alloc((size_t)E * 4);
  int* bsum1 = (int*)alloc(256 * 4);
  int* bsum2 = (int*)alloc(256 * 4);

  float* out_op = (float*)d_out;
  float* out_mc = out_op + (size_t)n_op * 64;

  init_kernel<<<512, 256, 0, stream>>>(ei, (const unsigned short*)op_nodes,
                                       flags, cnt1, n_mc, cnt2, n_op);

  int nbo = (n_op + 3) / 4, nbm = (n_mc + 3) / 4;
  int nbe = (E + 255) / 256;
  front_kernel<<<nbo + nbm + 256 + nbe, 256, 0, stream>>>(
      op_nodes, W_op, b_op, mc_nodes, W_mc, b_mc, W_om, att_om, W_mo, att_mo,
      ei, flags, vj_om, Wrt_om, vj_mo, Wrt_mo, h_op, ea_op, h_mc, cnt1, cnt2,
      n_op, n_mc, E, nbo, nbm);

  int nb1 = (n_mc + 2047) / 2048, nb2 = (n_op + 2047) / 2048;
  scan_bsum2<<<nb1 + nb2, 256, 0, stream>>>(cnt1, n_mc, nb1, cnt2, n_op, bsum1,
                                            bsum2);
  scan_write2<<<nb1 + nb2, 256, 0, stream>>>(cnt1, n_mc, nb1, bsum1, offs1,
                                             cur1, cnt2, n_op, nb2, bsum2,
                                             offs2, cur2);
  fill_edges<<<nbe, 256, 0, stream>>>(ei, E, flags, cur1, srcs1, cur2, srcs2);

  // GAT1: op -> mc (writes out_mc f32 + h_mc2 bf16 + ea_mc)
  gat_fused<true, true><<<(n_mc + 15) / 16, 256, 0, stream>>>(
      n_mc, offs1, srcs1, ea_op, h_op, Wrt_om, h_mc, out_mc, h_mc2, vj_mo,
      ea_mc);
  // GAT2: mc -> op (src = h_mc2 bf16)
  gat_fused<false, false><<<(n_op + 15) / 16, 256, 0, stream>>>(
      n_op, offs2, srcs2, ea_mc, h_mc2, Wrt_mo, h_op, out_op, (bf16*)nullptr,
      (const float*)nullptr, (float*)nullptr);
}

// Round 11
// 233.478 us; speedup vs baseline: 1.4963x; 1.0286x over previous
//
#include <hip/hip_runtime.h>
#include <hip/hip_bf16.h>

using bf16 = __hip_bfloat16;
typedef __attribute__((ext_vector_type(8))) short short8;
typedef __attribute__((ext_vector_type(4))) float f32x4;

__device__ __forceinline__ unsigned short f2bf(float f) {
  bf16 h = __float2bfloat16(f);
  return *reinterpret_cast<unsigned short*>(&h);
}
__device__ __forceinline__ float bf2f(unsigned short u) {
  return __uint_as_float(((unsigned)u) << 16);
}

__device__ __forceinline__ float loadf(const void* p, int i, int is_f32) {
  if (is_f32) return ((const float*)p)[i];
  return __bfloat162float(((const bf16*)p)[i]);
}

// ---------------------------------------------------------------------------
// init: zero counters + dtype detection (block 0)
// flags[0] = floats are f32, flags[1] = edges are int64
// ---------------------------------------------------------------------------
__global__ __launch_bounds__(256) void init_kernel(
    const int* __restrict__ ei, const unsigned short* __restrict__ x,
    int* __restrict__ flags, int* __restrict__ cnt1, int n1,
    int* __restrict__ cnt2, int n2) {
  int t = threadIdx.x;
  int g = blockIdx.x * 256 + t;
  int stride = gridDim.x * 256;
  for (int i = g; i < n1; i += stride) cnt1[i] = 0;
  for (int i = g; i < n2; i += stride) cnt2[i] = 0;
  if (blockIdx.x == 0) {
    __shared__ int red[256];
    int o = 0, big = 0;
    for (int i = t; i < 2048; i += 256) {
      o |= ei[2 * i + 1];
      float v = __uint_as_float(((unsigned)x[2 * i]) << 16);
      if (!(fabsf(v) < 1000.f)) big = 1;
    }
    red[t] = o;
    __syncthreads();
    for (int d = 128; d > 0; d >>= 1) {
      if (t < d) red[t] |= red[t + d];
      __syncthreads();
    }
    int o_all = red[0];
    __syncthreads();
    red[t] = big;
    __syncthreads();
    for (int d = 128; d > 0; d >>= 1) {
      if (t < d) red[t] |= red[t + d];
      __syncthreads();
    }
    if (t == 0) {
      flags[0] = red[0];
      flags[1] = (o_all == 0) ? 1 : 0;
    }
  }
}

__device__ __forceinline__ int edge_src(const int* ei, int E, int e, int i64) {
  return i64 ? ei[2 * e] : ei[e];
}
__device__ __forceinline__ int edge_dst(const int* ei, int E, int e, int i64) {
  return i64 ? ei[2 * E + 2 * e] : ei[E + e];
}

// ---------------------------------------------------------------------------
// node transform: 4 nodes per wave; W/bias/vj held in registers.
// ea[n][h] = exp(h . v_j[h]) via 10-shuffle multi-value butterfly per node.
// ---------------------------------------------------------------------------
template <int FIN>
__device__ __forceinline__ void node_body4(
    const void* x, const void* W, const void* b, int is_f32,
    const float* vj, bf16* h_out, float* ea_out, int n0, int N) {
  int lane = threadIdx.x & 63;
  float wreg[FIN];
#pragma unroll
  for (int f = 0; f < FIN; ++f) wreg[f] = loadf(W, lane * FIN + f, is_f32);
  float bias = loadf(b, lane, is_f32);
  float vjreg[8];
  if (ea_out) {
#pragma unroll
    for (int h = 0; h < 8; ++h) vjreg[h] = vj[h * 64 + lane];
  }
#pragma unroll
  for (int j = 0; j < 4; ++j) {
    int n = n0 + j;
    if (n >= N) break;  // wave-uniform
    float acc = bias;
#pragma unroll
    for (int f = 0; f < FIN; ++f)
      acc += loadf(x, n * FIN + f, is_f32) * wreg[f];
    float hv = acc > 0.f ? acc : expm1f(acc);
    h_out[(unsigned)(n << 6) + lane] = __float2bfloat16(hv);
    if (ea_out) {
      float p[8];
#pragma unroll
      for (int h = 0; h < 8; ++h) p[h] = hv * vjreg[h];
#pragma unroll
      for (int i = 0; i < 4; ++i) {
        float send = (lane & 4) ? p[i] : p[i + 4];
        float keep = (lane & 4) ? p[i + 4] : p[i];
        p[i] = keep + __shfl_xor(send, 4, 64);
      }
#pragma unroll
      for (int i = 0; i < 2; ++i) {
        float send = (lane & 2) ? p[i] : p[i + 2];
        float keep = (lane & 2) ? p[i + 2] : p[i];
        p[i] = keep + __shfl_xor(send, 2, 64);
      }
      {
        float send = (lane & 1) ? p[0] : p[1];
        float keep = (lane & 1) ? p[1] : p[0];
        p[0] = keep + __shfl_xor(send, 1, 64);
      }
      p[0] += __shfl_xor(p[0], 8, 64);
      p[0] += __shfl_xor(p[0], 16, 64);
      p[0] += __shfl_xor(p[0], 32, 64);
      if (lane < 8) ea_out[(unsigned)(n << 3) + lane] = __expf(p[0]);
    }
  }
}

// ---------------------------------------------------------------------------
// front: node(op) | node(mc) | prep(weights) | count(edges) in ONE launch
// ---------------------------------------------------------------------------
__global__ __launch_bounds__(256) void front_kernel(
    const void* __restrict__ x_op, const void* __restrict__ W_op,
    const void* __restrict__ b_op, const void* __restrict__ x_mc,
    const void* __restrict__ W_mc, const void* __restrict__ b_mc,
    const void* __restrict__ W1, const void* __restrict__ att1,
    const void* __restrict__ W2, const void* __restrict__ att2,
    const int* __restrict__ ei, const int* __restrict__ flags,
    float* __restrict__ vj1, bf16* __restrict__ Wrt1, float* __restrict__ vj2,
    bf16* __restrict__ Wrt2, bf16* __restrict__ h_op,
    float* __restrict__ ea_op, bf16* __restrict__ h_mc,
    int* __restrict__ cnt_dst, int* __restrict__ cnt_src, int n_op, int n_mc,
    int E, int nbo, int nbm) {
  int bid = blockIdx.x;
  int is_f32 = flags[0];
  if (bid < nbo) {
    int n0 = bid * 16 + (threadIdx.x >> 6) * 4;
    if (n0 < n_op)
      node_body4<4>(x_op, W_op, b_op, is_f32, vj1, h_op, ea_op, n0, n_op);
  } else if (bid < nbo + nbm) {
    int n0 = (bid - nbo) * 16 + (threadIdx.x >> 6) * 4;
    if (n0 < n_mc)
      node_body4<2>(x_mc, W_mc, b_mc, is_f32, nullptr, h_mc, nullptr, n0, n_mc);
  } else if (bid < nbo + nbm + 256) {
    int pb = bid - nbo - nbm;
    int side = pb >= 128;
    const void* W = side ? W2 : W1;
    const void* att = side ? att2 : att1;
    float* vj = side ? vj2 : vj1;
    bf16* Wrt = side ? Wrt2 : Wrt1;
    int tt = (pb & 127) * 256 + threadIdx.x;
    if (tt < 32768) {
      int c = tt >> 9, k = tt & 511;
      int f = k >> 3, h = k & 7;
      Wrt[tt] = __float2bfloat16(loadf(W, ((h << 6) + c) * 64 + f, is_f32));
    }
    if (tt < 512) {
      int hh = tt >> 6, ff = tt & 63;
      float s = 0.f;
      for (int cc = 0; cc < 64; ++cc)
        s += loadf(att, hh * 128 + 64 + cc, is_f32) *
             loadf(W, ((hh << 6) + cc) * 64 + ff, is_f32);
      vj[tt] = s;
    }
  } else {
    int i64 = flags[1];
    int e = (bid - nbo - nbm - 256) * 256 + threadIdx.x;
    if (e < E) {
      atomicAdd(&cnt_dst[edge_dst(ei, E, e, i64)], 1);
      atomicAdd(&cnt_src[edge_src(ei, E, e, i64)], 1);
    }
  }
}

// ---------------------------------------------------------------------------
// CSR scan (2 kernels) + fill
// ---------------------------------------------------------------------------
__global__ __launch_bounds__(256) void scan_bsum2(
    const int* __restrict__ cnt1, int n1, int nb1, const int* __restrict__ cnt2,
    int n2, int* __restrict__ bsum1, int* __restrict__ bsum2) {
  __shared__ int red[256];
  int t = threadIdx.x;
  int side = (int)blockIdx.x >= nb1;
  const int* cnt = side ? cnt2 : cnt1;
  int n = side ? n2 : n1;
  int blk = side ? (blockIdx.x - nb1) : blockIdx.x;
  int base = blk * 2048 + t * 8;
  int s = 0;
#pragma unroll
  for (int i = 0; i < 8; ++i)
    if (base + i < n) s += cnt[base + i];
  red[t] = s;
  __syncthreads();
  for (int d = 128; d > 0; d >>= 1) {
    if (t < d) red[t] += red[t + d];
    __syncthreads();
  }
  if (t == 0) (side ? bsum2 : bsum1)[blk] = red[0];
}

__global__ __launch_bounds__(256) void scan_write2(
    const int* __restrict__ cnt1, int n1, int nb1,
    const int* __restrict__ bsum1, int* __restrict__ offs1,
    int* __restrict__ cur1, const int* __restrict__ cnt2, int n2, int nb2,
    const int* __restrict__ bsum2, int* __restrict__ offs2,
    int* __restrict__ cur2) {
  __shared__ int red[256];
  __shared__ int base_s;
  int t = threadIdx.x;
  int side = (int)blockIdx.x >= nb1;
  const int* cnt = side ? cnt2 : cnt1;
  const int* bsum = side ? bsum2 : bsum1;
  int* offs = side ? offs2 : offs1;
  int* cur = side ? cur2 : cur1;
  int n = side ? n2 : n1;
  int nb = side ? nb2 : nb1;
  int blk = side ? (blockIdx.x - nb1) : blockIdx.x;
  if (t == 0) {
    int b = 0;
    for (int i = 0; i < blk; ++i) b += bsum[i];
    base_s = b;
  }
  int base = blk * 2048 + t * 8;
  int c[8];
  int s = 0;
#pragma unroll
  for (int i = 0; i < 8; ++i) {
    c[i] = (base + i < n) ? cnt[base + i] : 0;
    s += c[i];
  }
  red[t] = s;
  __syncthreads();
  for (int d = 1; d < 256; d <<= 1) {
    int v = red[t];
    int add = (t >= d) ? red[t - d] : 0;
    __syncthreads();
    red[t] = v + add;
    __syncthreads();
  }
  int run = base_s + red[t] - s;
#pragma unroll
  for (int i = 0; i < 8; ++i) {
    if (base + i < n) {
      offs[base + i] = run;
      cur[base + i] = run;
      run += c[i];
    }
  }
  if (blk == nb - 1 && t == 255) offs[n] = base_s + red[255];
}

__global__ __launch_bounds__(256) void fill_edges(
    const int* __restrict__ ei, int E, const int* __restrict__ flags,
    int* __restrict__ cur1, int* __restrict__ srcs1, int* __restrict__ cur2,
    int* __restrict__ srcs2) {
  int i64 = flags[1];
  int e = blockIdx.x * blockDim.x + threadIdx.x;
  if (e < E) {
    int s = edge_src(ei, E, e, i64), d = edge_dst(ei, E, e, i64);
    int p = atomicAdd(&cur1[d], 1);
    srcs1[p] = s;
    int q = atomicAdd(&cur2[s], 1);
    srcs2[q] = d;
  }
}

// ---------------------------------------------------------------------------
// fused GAT v6: statless, quarter-wave streams, SOFTWARE-PIPELINED rounds
// (quad-batched independent x loads), parallel staging (no LDS round-trip on
// the ea chain), 32-bit addressing, h_res prefetch, ajp unioned onto ew_s.
// ---------------------------------------------------------------------------
template <bool WRITE_AJ, bool WRITE_BF>
__global__ __launch_bounds__(256) void gat_fused(
    int Nd, const int* __restrict__ offs, const int* __restrict__ srcs,
    const float* __restrict__ ea, const bf16* __restrict__ h_src,
    const bf16* __restrict__ Wrt, const bf16* __restrict__ h_res,
    float* __restrict__ out_f32, bf16* __restrict__ out_bf,
    const float* __restrict__ vj_next, float* __restrict__ ea_next) {
  __shared__ __align__(16) unsigned short Zl[16 * 520];  // 16.3 KB
  __shared__ int srcs_sw[4][65];                         // 1 KB
  __shared__ __align__(16) float ew_s[4][528];           // 8.25 KB
  float(*ajp)[16][8] = reinterpret_cast<float(*)[16][8]>(&ew_s[0][0]);

  int t = threadIdx.x;
  int wv = t >> 6, lane = t & 63;
  int d0 = blockIdx.x * 16;
  int sj = lane >> 4;  // dst slot within wave
  int fq = lane & 15;  // feature quad

  int dlo = d0 + wv * 4;
  int wo0 = offs[min(dlo + 0, Nd)];
  int wo1 = offs[min(dlo + 1, Nd)];
  int wo2 = offs[min(dlo + 2, Nd)];
  int wo3 = offs[min(dlo + 3, Nd)];
  int wo4 = offs[min(dlo + 4, Nd)];
  int woj = sj == 0 ? wo0 : sj == 1 ? wo1 : sj == 2 ? wo2 : wo3;
  int woj1 = sj == 0 ? wo1 : sj == 1 ? wo2 : sj == 2 ? wo3 : wo4;

  float z[8][4];
#pragma unroll
  for (int h = 0; h < 8; ++h)
#pragma unroll
    for (int f = 0; f < 4; ++f) z[h][f] = 0.f;
  float s8[8];
#pragma unroll
  for (int h = 0; h < 8; ++h) s8[h] = 0.f;

  const unsigned short* hsrc_u = (const unsigned short*)h_src;

  for (int cb = wo0; cb < wo4; cb += 64) {
    int cn = min(64, wo4 - cb);
    // parallel staging: srcs -> LDS; ea gathered via DIRECT global srcs read
    for (int i = lane; i < cn + 1; i += 64)
      srcs_sw[wv][i] = (i < cn) ? srcs[cb + i] : 0;
    for (int i = lane; i < (cn + 1) * 8; i += 64) {
      int e = i >> 3;
      int src2 = (e < cn) ? srcs[cb + e] : 0;
      ew_s[wv][i] = (e < cn) ? ea[((unsigned)src2 << 3) + (i & 7)] : 0.f;
    }
    int c0 = max(cb, woj) - cb;
    int e1 = min(cb + cn, woj1) - cb;
    int rl = max(e1 - c0, 0);
    int rmax = max(rl, __shfl_xor(rl, 16, 64));
    rmax = max(rmax, __shfl_xor(rmax, 32, 64));
    // quad-pipelined rounds: 4 independent x loads in flight
    for (int r0 = 0; r0 < rmax; r0 += 4) {
      int i2q[4];
      ushort4 uq[4];
#pragma unroll
      for (int q = 0; q < 4; ++q) {
        int r = r0 + q;
        int i2 = (r < rl) ? (c0 + r) : cn;
        i2q[q] = i2;
        int src = srcs_sw[wv][i2];
        uq[q] = *(const ushort4*)(hsrc_u + (((unsigned)src) << 6) + (fq << 2));
      }
#pragma unroll
      for (int q = 0; q < 4; ++q) {
        int i2 = i2q[q];
        float4 lo4 = *(const float4*)&ew_s[wv][i2 * 8];
        float4 hi4 = *(const float4*)&ew_s[wv][i2 * 8 + 4];
        float x0 = bf2f(uq[q].x), x1 = bf2f(uq[q].y);
        float x2 = bf2f(uq[q].z), x3 = bf2f(uq[q].w);
        z[0][0] += lo4.x * x0; z[0][1] += lo4.x * x1; z[0][2] += lo4.x * x2; z[0][3] += lo4.x * x3;
        z[1][0] += lo4.y * x0; z[1][1] += lo4.y * x1; z[1][2] += lo4.y * x2; z[1][3] += lo4.y * x3;
        z[2][0] += lo4.z * x0; z[2][1] += lo4.z * x1; z[2][2] += lo4.z * x2; z[2][3] += lo4.z * x3;
        z[3][0] += lo4.w * x0; z[3][1] += lo4.w * x1; z[3][2] += lo4.w * x2; z[3][3] += lo4.w * x3;
        z[4][0] += hi4.x * x0; z[4][1] += hi4.x * x1; z[4][2] += hi4.x * x2; z[4][3] += hi4.x * x3;
        z[5][0] += hi4.y * x0; z[5][1] += hi4.y * x1; z[5][2] += hi4.y * x2; z[5][3] += hi4.y * x3;
        z[6][0] += hi4.z * x0; z[6][1] += hi4.z * x1; z[6][2] += hi4.z * x2; z[6][3] += hi4.z * x3;
        z[7][0] += hi4.w * x0; z[7][1] += hi4.w * x1; z[7][2] += hi4.w * x2; z[7][3] += hi4.w * x3;
        s8[0] += lo4.x; s8[1] += lo4.y; s8[2] += lo4.z; s8[3] += lo4.w;
        s8[4] += hi4.x; s8[5] += hi4.y; s8[6] += hi4.z; s8[7] += hi4.w;
      }
    }
  }

  // normalize at pack time -> Zl bf16, row = wv*4+sj, k' = (fq*4+fi)*8 + h
  float si[8];
#pragma unroll
  for (int h = 0; h < 8; ++h) si[h] = s8[h] > 0.f ? 1.f / s8[h] : 0.f;
  int row = wv * 4 + sj;
#pragma unroll
  for (int fi = 0; fi < 4; ++fi) {
    int4 pk;
    pk.x = ((int)f2bf(z[1][fi] * si[1]) << 16) | f2bf(z[0][fi] * si[0]);
    pk.y = ((int)f2bf(z[3][fi] * si[3]) << 16) | f2bf(z[2][fi] * si[2]);
    pk.z = ((int)f2bf(z[5][fi] * si[5]) << 16) | f2bf(z[4][fi] * si[4]);
    pk.w = ((int)f2bf(z[7][fi] * si[7]) << 16) | f2bf(z[6][fi] * si[6]);
    *(int4*)&Zl[row * 520 + (fq * 4 + fi) * 8] = pk;
  }

  // prefetch residual (independent of Zl) before the barrier
  int arow = lane & 15;
  int kg = lane >> 4;
  int col = wv * 16 + arow;
  float res[4];
#pragma unroll
  for (int r = 0; r < 4; ++r) {
    int d = d0 + kg * 4 + r;
    res[r] = (d < Nd)
                 ? __bfloat162float(h_res[(unsigned)(d << 6) + col])
                 : 0.f;
  }
  __syncthreads();

  // MFMA epilogue: wave wv computes rows 0..15, cols wv*16..wv*16+15
  f32x4 acc = {0.f, 0.f, 0.f, 0.f};
#pragma unroll
  for (int kt = 0; kt < 16; ++kt) {
    int kbase = kt * 32 + kg * 8;
    short8 a = *(const short8*)&Zl[arow * 520 + kbase];
    short8 b = *(const short8*)&Wrt[(unsigned)((wv * 16 + arow) * 512 + kbase)];
    acc = __builtin_amdgcn_mfma_f32_16x16x32_bf16(a, b, acc, 0, 0, 0);
  }

  float o_r[4];
#pragma unroll
  for (int r = 0; r < 4; ++r) {
    int d = d0 + kg * 4 + r;
    float o = 0.f;
    if (d < Nd) {
      float v = res[r] + 0.125f * acc[r];
      o = v > 0.f ? v : expm1f(v);
      out_f32[(unsigned)(d << 6) + col] = o;
      if (WRITE_BF) out_bf[(unsigned)(d << 6) + col] = __float2bfloat16(o);
    }
    o_r[r] = o;
  }

  if (WRITE_AJ) {
#pragma unroll
    for (int r = 0; r < 4; ++r) {
      int dloc = kg * 4 + r;
      float p[8];
#pragma unroll
      for (int h = 0; h < 8; ++h) p[h] = o_r[r] * vj_next[h * 64 + col];
#pragma unroll
      for (int i = 0; i < 4; ++i) {
        float send = (arow & 4) ? p[i] : p[i + 4];
        float keep = (arow & 4) ? p[i + 4] : p[i];
        p[i] = keep + __shfl_xor(send, 4, 64);
      }
#pragma unroll
      for (int i = 0; i < 2; ++i) {
        float send = (arow & 2) ? p[i] : p[i + 2];
        float keep = (arow & 2) ? p[i + 2] : p[i];
        p[i] = keep + __shfl_xor(send, 2, 64);
      }
      {
        float send = (arow & 1) ? p[0] : p[1];
        float keep = (arow & 1) ? p[1] : p[0];
        p[0] = keep + __shfl_xor(send, 1, 64);
      }
      p[0] += __shfl_xor(p[0], 8, 64);
      if (arow < 8) ajp[wv][dloc][arow] = p[0];
    }
    __syncthreads();
    if (t < 128) {
      int dloc = t >> 3, h = t & 7;
      int d = d0 + dloc;
      if (d < Nd) {
        float s = ajp[0][dloc][h] + ajp[1][dloc][h] + ajp[2][dloc][h] +
                  ajp[3][dloc][h];
        ea_next[(unsigned)(d << 3) + h] = __expf(s);
      }
    }
  }
}

// ---------------------------------------------------------------------------
extern "C" void kernel_launch(void* const* d_in, const int* in_sizes, int n_in,
                              void* d_out, int out_size, void* d_ws,
                              size_t ws_size, hipStream_t stream) {
  const void* op_nodes = d_in[0];
  const void* mc_nodes = d_in[1];
  const int* ei        = (const int*)d_in[2];
  const void* W_op     = d_in[3];
  const void* b_op     = d_in[4];
  const void* W_mc     = d_in[5];
  const void* b_mc     = d_in[6];
  const void* W_om     = d_in[7];
  const void* att_om   = d_in[8];
  const void* W_mo     = d_in[9];
  const void* att_mo   = d_in[10];

  int n_op = in_sizes[0] / 4;
  int n_mc = in_sizes[1] / 2;
  int E    = in_sizes[2] / 2;

  char* ws = (char*)d_ws;
  size_t off = 0;
  auto alloc = [&](size_t bytes) -> void* {
    void* p = ws + off;
    off = (off + bytes + 255) & ~(size_t)255;
    return p;
  };
  int* flags   = (int*)alloc(16);
  bf16* h_op   = (bf16*)alloc((size_t)n_op * 64 * 2);
  bf16* h_mc   = (bf16*)alloc((size_t)n_mc * 64 * 2);
  bf16* h_mc2  = (bf16*)alloc((size_t)n_mc * 64 * 2);
  float* ea_op = (float*)alloc((size_t)n_op * 8 * 4);
  float* ea_mc = (float*)alloc((size_t)n_mc * 8 * 4);
  float* vj_om = (float*)alloc(512 * 4);
  float* vj_mo = (float*)alloc(512 * 4);
  bf16* Wrt_om = (bf16*)alloc(32768 * 2);
  bf16* Wrt_mo = (bf16*)alloc(32768 * 2);
  int* cnt1  = (int*)alloc((size_t)n_mc * 4);
  int* cnt2  = (int*)alloc((size_t)n_op * 4);
  int* offs1 = (int*)alloc((size_t)(n_mc + 1) * 4);
  int* cur1  = (int*)alloc((size_t)n_mc * 4);
  int* srcs1 = (int*)alloc((size_t)E * 4);
  int* offs2 = (int*)alloc((size_t)(n_op + 1) * 4);
  int* cur2  = (int*)alloc((size_t)n_op * 4);
  int* srcs2 = (int*)alloc((size_t)E * 4);
  int* bsum1 = (int*)alloc(256 * 4);
  int* bsum2 = (int*)alloc(256 * 4);

  float* out_op = (float*)d_out;
  float* out_mc = out_op + (size_t)n_op * 64;

  init_kernel<<<512, 256, 0, stream>>>(ei, (const unsigned short*)op_nodes,
                                       flags, cnt1, n_mc, cnt2, n_op);

  int nbo = (n_op + 15) / 16, nbm = (n_mc + 15) / 16;
  int nbe = (E + 255) / 256;
  front_kernel<<<nbo + nbm + 256 + nbe, 256, 0, stream>>>(
      op_nodes, W_op, b_op, mc_nodes, W_mc, b_mc, W_om, att_om, W_mo, att_mo,
      ei, flags, vj_om, Wrt_om, vj_mo, Wrt_mo, h_op, ea_op, h_mc, cnt1, cnt2,
      n_op, n_mc, E, nbo, nbm);

  int nb1 = (n_mc + 2047) / 2048, nb2 = (n_op + 2047) / 2048;
  scan_bsum2<<<nb1 + nb2, 256, 0, stream>>>(cnt1, n_mc, nb1, cnt2, n_op, bsum1,
                                            bsum2);
  scan_write2<<<nb1 + nb2, 256, 0, stream>>>(cnt1, n_mc, nb1, bsum1, offs1,
                                             cur1, cnt2, n_op, nb2, bsum2,
                                             offs2, cur2);
  fill_edges<<<nbe, 256, 0, stream>>>(ei, E, flags, cur1, srcs1, cur2, srcs2);

  // GAT1: op -> mc (writes out_mc f32 + h_mc2 bf16 + ea_mc)
  gat_fused<true, true><<<(n_mc + 15) / 16, 256, 0, stream>>>(
      n_mc, offs1, srcs1, ea_op, h_op, Wrt_om, h_mc, out_mc, h_mc2, vj_mo,
      ea_mc);
  // GAT2: mc -> op (src = h_mc2 bf16)
  gat_fused<false, false><<<(n_op + 15) / 16, 256, 0, stream>>>(
      n_op, offs2, srcs2, ea_mc, h_mc2, Wrt_mo, h_op, out_op, (bf16*)nullptr,
      (const float*)nullptr, (float*)nullptr);
}

// Round 12
// 208.341 us; speedup vs baseline: 1.6768x; 1.1207x over previous
//
#include <hip/hip_runtime.h>
#include <hip/hip_bf16.h>

using bf16 = __hip_bfloat16;
typedef __attribute__((ext_vector_type(8))) short short8;
typedef __attribute__((ext_vector_type(4))) float f32x4;

__device__ __forceinline__ unsigned short f2bf(float f) {
  bf16 h = __float2bfloat16(f);
  return *reinterpret_cast<unsigned short*>(&h);
}
__device__ __forceinline__ float bf2f(unsigned short u) {
  return __uint_as_float(((unsigned)u) << 16);
}

__device__ __forceinline__ float loadf(const void* p, int i, int is_f32) {
  if (is_f32) return ((const float*)p)[i];
  return __bfloat162float(((const bf16*)p)[i]);
}

// ---------------------------------------------------------------------------
// init: zero counters + dtype detection (block 0)
// flags[0] = floats are f32, flags[1] = edges are int64
// ---------------------------------------------------------------------------
__global__ __launch_bounds__(256) void init_kernel(
    const int* __restrict__ ei, const unsigned short* __restrict__ x,
    int* __restrict__ flags, int* __restrict__ cnt1, int n1,
    int* __restrict__ cnt2, int n2) {
  int t = threadIdx.x;
  int g = blockIdx.x * 256 + t;
  int stride = gridDim.x * 256;
  for (int i = g; i < n1; i += stride) cnt1[i] = 0;
  for (int i = g; i < n2; i += stride) cnt2[i] = 0;
  if (blockIdx.x == 0) {
    __shared__ int red[256];
    int o = 0, big = 0;
    for (int i = t; i < 2048; i += 256) {
      o |= ei[2 * i + 1];
      float v = __uint_as_float(((unsigned)x[2 * i]) << 16);
      if (!(fabsf(v) < 1000.f)) big = 1;
    }
    red[t] = o;
    __syncthreads();
    for (int d = 128; d > 0; d >>= 1) {
      if (t < d) red[t] |= red[t + d];
      __syncthreads();
    }
    int o_all = red[0];
    __syncthreads();
    red[t] = big;
    __syncthreads();
    for (int d = 128; d > 0; d >>= 1) {
      if (t < d) red[t] |= red[t + d];
      __syncthreads();
    }
    if (t == 0) {
      flags[0] = red[0];
      flags[1] = (o_all == 0) ? 1 : 0;
    }
  }
}

__device__ __forceinline__ int edge_src(const int* ei, int E, int e, int i64) {
  return i64 ? ei[2 * e] : ei[e];
}
__device__ __forceinline__ int edge_dst(const int* ei, int E, int e, int i64) {
  return i64 ? ei[2 * E + 2 * e] : ei[E + e];
}

// ---------------------------------------------------------------------------
// node transform: 4 nodes per wave; W/bias/vj in registers.
// ea[n][h] = exp(h . v_j[h]) stored as bf16x8 via 10-shuffle butterfly.
// ---------------------------------------------------------------------------
template <int FIN>
__device__ __forceinline__ void node_body4(
    const void* x, const void* W, const void* b, int is_f32,
    const float* vj, bf16* h_out, unsigned short* ea_out, int n0, int N) {
  int lane = threadIdx.x & 63;
  float wreg[FIN];
#pragma unroll
  for (int f = 0; f < FIN; ++f) wreg[f] = loadf(W, lane * FIN + f, is_f32);
  float bias = loadf(b, lane, is_f32);
  float vjreg[8];
  if (ea_out) {
#pragma unroll
    for (int h = 0; h < 8; ++h) vjreg[h] = vj[h * 64 + lane];
  }
#pragma unroll
  for (int j = 0; j < 4; ++j) {
    int n = n0 + j;
    if (n >= N) break;  // wave-uniform
    float acc = bias;
#pragma unroll
    for (int f = 0; f < FIN; ++f)
      acc += loadf(x, n * FIN + f, is_f32) * wreg[f];
    float hv = acc > 0.f ? acc : expm1f(acc);
    h_out[(unsigned)(n << 6) + lane] = __float2bfloat16(hv);
    if (ea_out) {
      float p[8];
#pragma unroll
      for (int h = 0; h < 8; ++h) p[h] = hv * vjreg[h];
#pragma unroll
      for (int i = 0; i < 4; ++i) {
        float send = (lane & 4) ? p[i] : p[i + 4];
        float keep = (lane & 4) ? p[i + 4] : p[i];
        p[i] = keep + __shfl_xor(send, 4, 64);
      }
#pragma unroll
      for (int i = 0; i < 2; ++i) {
        float send = (lane & 2) ? p[i] : p[i + 2];
        float keep = (lane & 2) ? p[i + 2] : p[i];
        p[i] = keep + __shfl_xor(send, 2, 64);
      }
      {
        float send = (lane & 1) ? p[0] : p[1];
        float keep = (lane & 1) ? p[1] : p[0];
        p[0] = keep + __shfl_xor(send, 1, 64);
      }
      p[0] += __shfl_xor(p[0], 8, 64);
      p[0] += __shfl_xor(p[0], 16, 64);
      p[0] += __shfl_xor(p[0], 32, 64);
      if (lane < 8) ea_out[(unsigned)(n << 3) + lane] = f2bf(__expf(p[0]));
    }
  }
}

// ---------------------------------------------------------------------------
// front: node(op) | node(mc) | prep(weights) | count(edges) in ONE launch
// ---------------------------------------------------------------------------
__global__ __launch_bounds__(256) void front_kernel(
    const void* __restrict__ x_op, const void* __restrict__ W_op,
    const void* __restrict__ b_op, const void* __restrict__ x_mc,
    const void* __restrict__ W_mc, const void* __restrict__ b_mc,
    const void* __restrict__ W1, const void* __restrict__ att1,
    const void* __restrict__ W2, const void* __restrict__ att2,
    const int* __restrict__ ei, const int* __restrict__ flags,
    float* __restrict__ vj1, bf16* __restrict__ Wrt1, float* __restrict__ vj2,
    bf16* __restrict__ Wrt2, bf16* __restrict__ h_op,
    unsigned short* __restrict__ ea_op, bf16* __restrict__ h_mc,
    int* __restrict__ cnt_dst, int* __restrict__ cnt_src, int n_op, int n_mc,
    int E, int nbo, int nbm) {
  int bid = blockIdx.x;
  int is_f32 = flags[0];
  if (bid < nbo) {
    int n0 = bid * 16 + (threadIdx.x >> 6) * 4;
    if (n0 < n_op)
      node_body4<4>(x_op, W_op, b_op, is_f32, vj1, h_op, ea_op, n0, n_op);
  } else if (bid < nbo + nbm) {
    int n0 = (bid - nbo) * 16 + (threadIdx.x >> 6) * 4;
    if (n0 < n_mc)
      node_body4<2>(x_mc, W_mc, b_mc, is_f32, nullptr, h_mc, nullptr, n0, n_mc);
  } else if (bid < nbo + nbm + 256) {
    int pb = bid - nbo - nbm;
    int side = pb >= 128;
    const void* W = side ? W2 : W1;
    const void* att = side ? att2 : att1;
    float* vj = side ? vj2 : vj1;
    bf16* Wrt = side ? Wrt2 : Wrt1;
    int tt = (pb & 127) * 256 + threadIdx.x;
    if (tt < 32768) {
      int c = tt >> 9, k = tt & 511;
      int f = k >> 3, h = k & 7;
      Wrt[tt] = __float2bfloat16(loadf(W, ((h << 6) + c) * 64 + f, is_f32));
    }
    if (tt < 512) {
      int hh = tt >> 6, ff = tt & 63;
      float s = 0.f;
      for (int cc = 0; cc < 64; ++cc)
        s += loadf(att, hh * 128 + 64 + cc, is_f32) *
             loadf(W, ((hh << 6) + cc) * 64 + ff, is_f32);
      vj[tt] = s;
    }
  } else {
    int i64 = flags[1];
    int e = (bid - nbo - nbm - 256) * 256 + threadIdx.x;
    if (e < E) {
      atomicAdd(&cnt_dst[edge_dst(ei, E, e, i64)], 1);
      atomicAdd(&cnt_src[edge_src(ei, E, e, i64)], 1);
    }
  }
}

// ---------------------------------------------------------------------------
// CSR scan (2 kernels) + fill
// ---------------------------------------------------------------------------
__global__ __launch_bounds__(256) void scan_bsum2(
    const int* __restrict__ cnt1, int n1, int nb1, const int* __restrict__ cnt2,
    int n2, int* __restrict__ bsum1, int* __restrict__ bsum2) {
  __shared__ int red[256];
  int t = threadIdx.x;
  int side = (int)blockIdx.x >= nb1;
  const int* cnt = side ? cnt2 : cnt1;
  int n = side ? n2 : n1;
  int blk = side ? (blockIdx.x - nb1) : blockIdx.x;
  int base = blk * 2048 + t * 8;
  int s = 0;
#pragma unroll
  for (int i = 0; i < 8; ++i)
    if (base + i < n) s += cnt[base + i];
  red[t] = s;
  __syncthreads();
  for (int d = 128; d > 0; d >>= 1) {
    if (t < d) red[t] += red[t + d];
    __syncthreads();
  }
  if (t == 0) (side ? bsum2 : bsum1)[blk] = red[0];
}

__global__ __launch_bounds__(256) void scan_write2(
    const int* __restrict__ cnt1, int n1, int nb1,
    const int* __restrict__ bsum1, int* __restrict__ offs1,
    int* __restrict__ cur1, const int* __restrict__ cnt2, int n2, int nb2,
    const int* __restrict__ bsum2, int* __restrict__ offs2,
    int* __restrict__ cur2) {
  __shared__ int red[256];
  __shared__ int base_s;
  int t = threadIdx.x;
  int side = (int)blockIdx.x >= nb1;
  const int* cnt = side ? cnt2 : cnt1;
  const int* bsum = side ? bsum2 : bsum1;
  int* offs = side ? offs2 : offs1;
  int* cur = side ? cur2 : cur1;
  int n = side ? n2 : n1;
  int nb = side ? nb2 : nb1;
  int blk = side ? (blockIdx.x - nb1) : blockIdx.x;
  if (t == 0) {
    int b = 0;
    for (int i = 0; i < blk; ++i) b += bsum[i];
    base_s = b;
  }
  int base = blk * 2048 + t * 8;
  int c[8];
  int s = 0;
#pragma unroll
  for (int i = 0; i < 8; ++i) {
    c[i] = (base + i < n) ? cnt[base + i] : 0;
    s += c[i];
  }
  red[t] = s;
  __syncthreads();
  for (int d = 1; d < 256; d <<= 1) {
    int v = red[t];
    int add = (t >= d) ? red[t - d] : 0;
    __syncthreads();
    red[t] = v + add;
    __syncthreads();
  }
  int run = base_s + red[t] - s;
#pragma unroll
  for (int i = 0; i < 8; ++i) {
    if (base + i < n) {
      offs[base + i] = run;
      cur[base + i] = run;
      run += c[i];
    }
  }
  if (blk == nb - 1 && t == 255) offs[n] = base_s + red[255];
}

__global__ __launch_bounds__(256) void fill_edges(
    const int* __restrict__ ei, int E, const int* __restrict__ flags,
    int* __restrict__ cur1, int* __restrict__ srcs1, int* __restrict__ cur2,
    int* __restrict__ srcs2) {
  int i64 = flags[1];
  int e = blockIdx.x * blockDim.x + threadIdx.x;
  if (e < E) {
    int s = edge_src(ei, E, e, i64), d = edge_dst(ei, E, e, i64);
    int p = atomicAdd(&cur1[d], 1);
    srcs1[p] = s;
    int q = atomicAdd(&cur2[s], 1);
    srcs2[q] = d;
  }
}

// ---------------------------------------------------------------------------
// fused GAT v7: ZERO-STAGING gather. 16 dsts/block, 4 dsts/wave, quarter-wave
// streams. Per round each quarter reads srcs / h_src-rowslice / ea(bf16x8)
// DIRECTLY from global (L2-hot), quad-batched for 12 loads in flight.
// No LDS except Zl (MFMA staging) + ajp. Statless softmax (ea pre-exp'd),
// 1/s folded into the bf16 pack. MFMA epilogue 16x512 @ 512x64.
// ---------------------------------------------------------------------------
template <bool WRITE_AJ, bool WRITE_BF>
__global__ __launch_bounds__(256) void gat_fused(
    int Nd, const int* __restrict__ offs, const int* __restrict__ srcs,
    const unsigned short* __restrict__ ea, const bf16* __restrict__ h_src,
    const bf16* __restrict__ Wrt, const bf16* __restrict__ h_res,
    float* __restrict__ out_f32, bf16* __restrict__ out_bf,
    const float* __restrict__ vj_next, unsigned short* __restrict__ ea_next) {
  __shared__ __align__(16) unsigned short Zl[16 * 520];  // 16.3 KB
  __shared__ float ajp[4][16][8];                        // 2 KB

  int t = threadIdx.x;
  int wv = t >> 6, lane = t & 63;
  int d0 = blockIdx.x * 16;
  int sj = lane >> 4;  // dst slot within wave
  int fq = lane & 15;  // feature quad

  int dlo = d0 + wv * 4;
  int wo0 = offs[min(dlo + 0, Nd)];
  int wo1 = offs[min(dlo + 1, Nd)];
  int wo2 = offs[min(dlo + 2, Nd)];
  int wo3 = offs[min(dlo + 3, Nd)];
  int wo4 = offs[min(dlo + 4, Nd)];
  int woj = sj == 0 ? wo0 : sj == 1 ? wo1 : sj == 2 ? wo2 : wo3;
  int woj1 = sj == 0 ? wo1 : sj == 1 ? wo2 : sj == 2 ? wo3 : wo4;
  int nj = woj1 - woj;

  float z[8][4];
#pragma unroll
  for (int h = 0; h < 8; ++h)
#pragma unroll
    for (int f = 0; f < 4; ++f) z[h][f] = 0.f;
  float s8[8];
#pragma unroll
  for (int h = 0; h < 8; ++h) s8[h] = 0.f;

  const unsigned short* hsrc_u = (const unsigned short*)h_src;

  int rmax = max(nj, __shfl_xor(nj, 16, 64));
  rmax = max(rmax, __shfl_xor(rmax, 32, 64));

  for (int r0 = 0; r0 < rmax; r0 += 4) {
    unsigned srcq[4];
#pragma unroll
    for (int q = 0; q < 4; ++q) {
      int r = r0 + q;
      srcq[q] = (r < nj) ? (unsigned)srcs[woj + r] : 0u;
    }
    ushort4 uq[4];
    short8 eq[4];
#pragma unroll
    for (int q = 0; q < 4; ++q) {
      unsigned s = srcq[q];
      uq[q] = *(const ushort4*)(hsrc_u + (s << 6) + (fq << 2));
      eq[q] = *(const short8*)(ea + (s << 3));
    }
#pragma unroll
    for (int q = 0; q < 4; ++q) {
      bool act = (r0 + q) < nj;
      float w[8];
#pragma unroll
      for (int h = 0; h < 8; ++h)
        w[h] = act ? bf2f((unsigned short)eq[q][h]) : 0.f;
      float x0 = bf2f(uq[q].x), x1 = bf2f(uq[q].y);
      float x2 = bf2f(uq[q].z), x3 = bf2f(uq[q].w);
#pragma unroll
      for (int h = 0; h < 8; ++h) {
        z[h][0] += w[h] * x0;
        z[h][1] += w[h] * x1;
        z[h][2] += w[h] * x2;
        z[h][3] += w[h] * x3;
        s8[h] += w[h];
      }
    }
  }

  // normalize at pack time -> Zl bf16, row = wv*4+sj, k' = (fq*4+fi)*8 + h
  float si[8];
#pragma unroll
  for (int h = 0; h < 8; ++h) si[h] = s8[h] > 0.f ? 1.f / s8[h] : 0.f;
  int row = wv * 4 + sj;
#pragma unroll
  for (int fi = 0; fi < 4; ++fi) {
    int4 pk;
    pk.x = ((int)f2bf(z[1][fi] * si[1]) << 16) | f2bf(z[0][fi] * si[0]);
    pk.y = ((int)f2bf(z[3][fi] * si[3]) << 16) | f2bf(z[2][fi] * si[2]);
    pk.z = ((int)f2bf(z[5][fi] * si[5]) << 16) | f2bf(z[4][fi] * si[4]);
    pk.w = ((int)f2bf(z[7][fi] * si[7]) << 16) | f2bf(z[6][fi] * si[6]);
    *(int4*)&Zl[row * 520 + (fq * 4 + fi) * 8] = pk;
  }

  // prefetch residual (independent of Zl) before the barrier
  int arow = lane & 15;
  int kg = lane >> 4;
  int col = wv * 16 + arow;
  float res[4];
#pragma unroll
  for (int r = 0; r < 4; ++r) {
    int d = d0 + kg * 4 + r;
    res[r] =
        (d < Nd) ? __bfloat162float(h_res[(unsigned)(d << 6) + col]) : 0.f;
  }
  __syncthreads();

  // MFMA epilogue: wave wv computes rows 0..15, cols wv*16..wv*16+15
  f32x4 acc = {0.f, 0.f, 0.f, 0.f};
#pragma unroll
  for (int kt = 0; kt < 16; ++kt) {
    int kbase = kt * 32 + kg * 8;
    short8 a = *(const short8*)&Zl[arow * 520 + kbase];
    short8 b = *(const short8*)&Wrt[(unsigned)((wv * 16 + arow) * 512 + kbase)];
    acc = __builtin_amdgcn_mfma_f32_16x16x32_bf16(a, b, acc, 0, 0, 0);
  }

  float o_r[4];
#pragma unroll
  for (int r = 0; r < 4; ++r) {
    int d = d0 + kg * 4 + r;
    float o = 0.f;
    if (d < Nd) {
      float v = res[r] + 0.125f * acc[r];
      o = v > 0.f ? v : expm1f(v);
      out_f32[(unsigned)(d << 6) + col] = o;
      if (WRITE_BF) out_bf[(unsigned)(d << 6) + col] = __float2bfloat16(o);
    }
    o_r[r] = o;
  }

  if (WRITE_AJ) {
#pragma unroll
    for (int r = 0; r < 4; ++r) {
      int dloc = kg * 4 + r;
      float p[8];
#pragma unroll
      for (int h = 0; h < 8; ++h) p[h] = o_r[r] * vj_next[h * 64 + col];
#pragma unroll
      for (int i = 0; i < 4; ++i) {
        float send = (arow & 4) ? p[i] : p[i + 4];
        float keep = (arow & 4) ? p[i + 4] : p[i];
        p[i] = keep + __shfl_xor(send, 4, 64);
      }
#pragma unroll
      for (int i = 0; i < 2; ++i) {
        float send = (arow & 2) ? p[i] : p[i + 2];
        float keep = (arow & 2) ? p[i + 2] : p[i];
        p[i] = keep + __shfl_xor(send, 2, 64);
      }
      {
        float send = (arow & 1) ? p[0] : p[1];
        float keep = (arow & 1) ? p[1] : p[0];
        p[0] = keep + __shfl_xor(send, 1, 64);
      }
      p[0] += __shfl_xor(p[0], 8, 64);
      if (arow < 8) ajp[wv][dloc][arow] = p[0];
    }
    __syncthreads();
    if (t < 128) {
      int dloc = t >> 3, h = t & 7;
      int d = d0 + dloc;
      if (d < Nd) {
        float s = ajp[0][dloc][h] + ajp[1][dloc][h] + ajp[2][dloc][h] +
                  ajp[3][dloc][h];
        ea_next[(unsigned)(d << 3) + h] = f2bf(__expf(s));
      }
    }
  }
}

// ---------------------------------------------------------------------------
extern "C" void kernel_launch(void* const* d_in, const int* in_sizes, int n_in,
                              void* d_out, int out_size, void* d_ws,
                              size_t ws_size, hipStream_t stream) {
  const void* op_nodes = d_in[0];
  const void* mc_nodes = d_in[1];
  const int* ei        = (const int*)d_in[2];
  const void* W_op     = d_in[3];
  const void* b_op     = d_in[4];
  const void* W_mc     = d_in[5];
  const void* b_mc     = d_in[6];
  const void* W_om     = d_in[7];
  const void* att_om   = d_in[8];
  const void* W_mo     = d_in[9];
  const void* att_mo   = d_in[10];

  int n_op = in_sizes[0] / 4;
  int n_mc = in_sizes[1] / 2;
  int E    = in_sizes[2] / 2;

  char* ws = (char*)d_ws;
  size_t off = 0;
  auto alloc = [&](size_t bytes) -> void* {
    void* p = ws + off;
    off = (off + bytes + 255) & ~(size_t)255;
    return p;
  };
  int* flags   = (int*)alloc(16);
  bf16* h_op   = (bf16*)alloc((size_t)n_op * 64 * 2);
  bf16* h_mc   = (bf16*)alloc((size_t)n_mc * 64 * 2);
  bf16* h_mc2  = (bf16*)alloc((size_t)n_mc * 64 * 2);
  unsigned short* ea_op = (unsigned short*)alloc((size_t)n_op * 8 * 2);
  unsigned short* ea_mc = (unsigned short*)alloc((size_t)n_mc * 8 * 2);
  float* vj_om = (float*)alloc(512 * 4);
  float* vj_mo = (float*)alloc(512 * 4);
  bf16* Wrt_om = (bf16*)alloc(32768 * 2);
  bf16* Wrt_mo = (bf16*)alloc(32768 * 2);
  int* cnt1  = (int*)alloc((size_t)n_mc * 4);
  int* cnt2  = (int*)alloc((size_t)n_op * 4);
  int* offs1 = (int*)alloc((size_t)(n_mc + 1) * 4);
  int* cur1  = (int*)alloc((size_t)n_mc * 4);
  int* srcs1 = (int*)alloc((size_t)E * 4);
  int* offs2 = (int*)alloc((size_t)(n_op + 1) * 4);
  int* cur2  = (int*)alloc((size_t)n_op * 4);
  int* srcs2 = (int*)alloc((size_t)E * 4);
  int* bsum1 = (int*)alloc(256 * 4);
  int* bsum2 = (int*)alloc(256 * 4);

  float* out_op = (float*)d_out;
  float* out_mc = out_op + (size_t)n_op * 64;

  init_kernel<<<512, 256, 0, stream>>>(ei, (const unsigned short*)op_nodes,
                                       flags, cnt1, n_mc, cnt2, n_op);

  int nbo = (n_op + 15) / 16, nbm = (n_mc + 15) / 16;
  int nbe = (E + 255) / 256;
  front_kernel<<<nbo + nbm + 256 + nbe, 256, 0, stream>>>(
      op_nodes, W_op, b_op, mc_nodes, W_mc, b_mc, W_om, att_om, W_mo, att_mo,
      ei, flags, vj_om, Wrt_om, vj_mo, Wrt_mo, h_op, ea_op, h_mc, cnt1, cnt2,
      n_op, n_mc, E, nbo, nbm);

  int nb1 = (n_mc + 2047) / 2048, nb2 = (n_op + 2047) / 2048;
  scan_bsum2<<<nb1 + nb2, 256, 0, stream>>>(cnt1, n_mc, nb1, cnt2, n_op, bsum1,
                                            bsum2);
  scan_write2<<<nb1 + nb2, 256, 0, stream>>>(cnt1, n_mc, nb1, bsum1, offs1,
                                             cur1, cnt2, n_op, nb2, bsum2,
                                             offs2, cur2);
  fill_edges<<<nbe, 256, 0, stream>>>(ei, E, flags, cur1, srcs1, cur2, srcs2);

  // GAT1: op -> mc (writes out_mc f32 + h_mc2 bf16 + ea_mc)
  gat_fused<true, true><<<(n_mc + 15) / 16, 256, 0, stream>>>(
      n_mc, offs1, srcs1, ea_op, h_op, Wrt_om, h_mc, out_mc, h_mc2, vj_mo,
      ea_mc);
  // GAT2: mc -> op (src = h_mc2 bf16)
  gat_fused<false, false><<<(n_op + 15) / 16, 256, 0, stream>>>(
      n_op, offs2, srcs2, ea_mc, h_mc2, Wrt_mo, h_op, out_op, (bf16*)nullptr,
      (const float*)nullptr, (unsigned short*)nullptr);
}